// Round 1
// 798.929 us; speedup vs baseline: 1.0448x; 1.0448x over previous
//
#include <hip/hip_runtime.h>
#include <hip/hip_bf16.h>

#define TT 512
#define HH 32

typedef __attribute__((ext_vector_type(8))) short short8;
typedef __attribute__((ext_vector_type(4))) float f32x4;

__device__ __forceinline__ float rcpf_(float x) { return __builtin_amdgcn_rcpf(x); }
// 2^x via a single v_exp_f32 (trans pipe). VALU->VALU deps are HW-interlocked.
__device__ __forceinline__ float expv_(float x) {
  float r;
  asm("v_exp_f32 %0, %1" : "=v"(r) : "v"(x));
  return r;
}
__device__ __forceinline__ float tanhf_(float z) {  // head only (1 use/block)
  float a = fabsf(z);
  float e = __expf(-2.f * a);
  return copysignf((1.f - e) * rcpf_(1.f + e), z);
}
__device__ __forceinline__ float bf16f_(ushort u) {
  uint b = (uint)u << 16;
  return __uint_as_float(b);
}

// cheap round-to-nearest bf16: add half-ulp then truncate. Exact-residual split.
__device__ __forceinline__ void split8_(const float* w, short8* hi, short8* lo) {
  union { short8 v; ushort u[8]; } H, L;
  #pragma unroll
  for (int i = 0; i < 8; ++i) {
    const uint hb = __float_as_uint(w[i]) + 0x8000u;
    H.u[i] = (ushort)(hb >> 16);
    const float hif = __uint_as_float(hb & 0xffff0000u);
    const uint lb = __float_as_uint(w[i] - hif) + 0x8000u;
    L.u[i] = (ushort)(lb >> 16);
  }
  *hi = H.v; *lo = L.v;
}

// LN one timestep (8 inputs in-lane) + bf16 hi/lo split -> X LDS row
__device__ __forceinline__ void stageX_(float4 va, float4 vb, int tloc, int col,
                                        ushort (*Xhi)[16][8], ushort (*Xlo)[16][8],
                                        const float* lnc) {
  float v[8] = {va.x, va.y, va.z, va.w, vb.x, vb.y, vb.z, vb.w};
  float s = 0.f;
  #pragma unroll
  for (int i = 0; i < 8; ++i) s += v[i];
  const float mu = s * 0.125f;
  float d[8], q2 = 0.f;
  #pragma unroll
  for (int i = 0; i < 8; ++i) { d[i] = v[i] - mu; q2 += d[i] * d[i]; }
  const float inv = __builtin_amdgcn_rsqf(fmaf(q2, 0.125f, 1e-5f));
  float xn[8];
  #pragma unroll
  for (int i = 0; i < 8; ++i) xn[i] = fmaf(d[i] * inv, lnc[i], lnc[8 + i]);
  short8 h8, l8;
  split8_(xn, &h8, &l8);
  *(short8*)&Xhi[tloc][col][0] = h8;
  *(short8*)&Xlo[tloc][col][0] = l8;
}

// Elementwise for 4 units. Preacts (incl. bias, folded into acc init) in acc.
// sigmoid/tanh via 2^x: sig(z)=1/(1+2^(-z*log2e)), tanh(z)=2*sig(2z)-1.
// One combined reciprocal per 4 gate denominators (1 rcp + 9 mul replaces
// 4 rcp) and one across the 4 units' tanh(c) denominators: 10 trans/unit ->
// ~6.25. Args clamped <=30 so 4-way denominator products stay < 2^120.
__device__ __forceinline__ void ew4_(const f32x4* acc, float* cst,
                                     ushort* dhi, ushort* dlo) {
  const float C1 = 1.44269504f;   // log2(e)
  const float C2 = 2.88539008f;   // 2*log2(e)
  float o_[4], e2[4];
  #pragma unroll
  for (int r = 0; r < 4; ++r) {
    const float ei = expv_(fminf(acc[0][r] * -C1, 30.f));
    const float ef = expv_(fminf(acc[1][r] * -C1, 30.f));
    const float eg = expv_(fminf(acc[2][r] * -C2, 30.f));
    const float eo = expv_(fminf(acc[3][r] * -C1, 30.f));
    const float di = 1.f + ei, df = 1.f + ef, dg = 1.f + eg, dq = 1.f + eo;
    const float p1 = di * df, p2 = dg * dq;
    const float rr = rcpf_(p1 * p2);
    const float r1 = rr * p2, r2 = rr * p1;           // 1/p1, 1/p2
    const float iv = r1 * df;                          // sigmoid(i)
    const float fv = r1 * di;                          // sigmoid(f)
    const float gv = fmaf(2.f, r2 * dq, -1.f);         // tanh(g)
    o_[r] = r2 * dg;                                   // sigmoid(o)
    const float c = fmaf(fv, cst[r], iv * gv);
    cst[r] = c;
    e2[r] = expv_(fminf(c * -C2, 30.f));
  }
  const float d0 = 1.f + e2[0], d1 = 1.f + e2[1];
  const float d2 = 1.f + e2[2], d3 = 1.f + e2[3];
  const float q1 = d0 * d1, q2 = d2 * d3;
  const float rq = rcpf_(q1 * q2);
  const float s1 = rq * q2, s2 = rq * q1;
  float hv[4];
  hv[0] = o_[0] * fmaf(2.f, s1 * d1, -1.f);
  hv[1] = o_[1] * fmaf(2.f, s1 * d0, -1.f);
  hv[2] = o_[2] * fmaf(2.f, s2 * d3, -1.f);
  hv[3] = o_[3] * fmaf(2.f, s2 * d2, -1.f);
  uint hp[2], lp[2];
  #pragma unroll
  for (int pr = 0; pr < 2; ++pr) {
    uint h16[2], l16[2];
    #pragma unroll
    for (int s = 0; s < 2; ++s) {
      const float h = hv[pr * 2 + s];
      const uint hb = __float_as_uint(h) + 0x8000u;
      const float hif = __uint_as_float(hb & 0xffff0000u);
      const uint lb = __float_as_uint(h - hif) + 0x8000u;
      h16[s] = hb >> 16;
      l16[s] = lb >> 16;
    }
    hp[pr] = h16[0] | (h16[1] << 16);
    lp[pr] = l16[0] | (l16[1] << 16);
  }
  *(uint2*)dhi = make_uint2(hp[0], hp[1]);
  *(uint2*)dlo = make_uint2(lp[0], lp[1]);
}

#define MFMA(A, B, C) __builtin_amdgcn_mfma_f32_16x16x32_bf16((A), (B), (C), 0, 0, 0)

// 256 threads = 4 waves; 16 batches/block. waves 0,1 = layer0, waves 2,3 = layer1.
// Wave w01 (=wv&1) owns m-tiles {2G+w01}: gate G rows 32G+16*w01+4q+r -> all 4
// gates of units 16*w01+4q+r live in one wave (in-register elementwise).
// Pipeline: iter j computes PA(j+1) (L0 waves) and PB(j) (L1 waves); 1 barrier/t.
// H rows padded 64B->80B: b128 start block 4*((20col+4q)/4 %32) spreads lanes
// 0-15 over all 8 bank-blocks (2-way max, free).
// X double-buffered by chunk parity; staging split across BOTH L0 waves (wave
// w01 stages tloc = 4*w01+q), halving the every-8th-iter straggler. LN consts
// live in registers (no LDS round trip, no prologue race).
// Bias is pre-loaded into the MFMA accumulator (acc init = bias), not added
// in ew4_.
__global__ __launch_bounds__(256, 1) void lstm_mfma(
    const float* __restrict__ X,
    const float* __restrict__ ln_g, const float* __restrict__ ln_b,
    const float* __restrict__ Wih0g, const float* __restrict__ Whh0g,
    const float* __restrict__ bih0, const float* __restrict__ bhh0,
    const float* __restrict__ Wih1g, const float* __restrict__ Whh1g,
    const float* __restrict__ bih1, const float* __restrict__ bhh1,
    const float* __restrict__ W1, const float* __restrict__ b1,
    const float* __restrict__ W2, const float* __restrict__ b2,
    float* __restrict__ out)
{
  __shared__ __align__(16) ushort H1hi[2][16][40], H1lo[2][16][40];
  __shared__ __align__(16) ushort H2hi[2][16][40], H2lo[2][16][40];
  __shared__ __align__(16) ushort Xhi[2][8][16][8], Xlo[2][8][16][8];

  const int tid = threadIdx.x;
  const int wv = tid >> 6;
  const int lane = tid & 63;
  const int q = lane >> 4;       // k-group / D row-group
  const int col = lane & 15;     // batch col (B/D) and A row (m)
  const int layer = wv >> 1;
  const int w01 = wv & 1;
  const int ubase = w01 * 16 + 4 * q;   // first owned unit
  const int b0 = blockIdx.x * 16;

  // ---- A-fragments (weights), once ----
  short8 aAh[4], aAl[4], aBh[4], aBl[4];
  #pragma unroll
  for (int G = 0; G < 4; ++G) {
    const int row = G * 32 + w01 * 16 + col;
    float w8[8];
    if (layer == 0) {
      if (q == 0) {
        const float4 a = ((const float4*)(Wih0g + row * 8))[0];
        const float4 b = ((const float4*)(Wih0g + row * 8))[1];
        w8[0]=a.x; w8[1]=a.y; w8[2]=a.z; w8[3]=a.w;
        w8[4]=b.x; w8[5]=b.y; w8[6]=b.z; w8[7]=b.w;
      } else {
        #pragma unroll
        for (int i = 0; i < 8; ++i) w8[i] = 0.f;
      }
    } else {
      const float4* P = (const float4*)(Wih1g + row * HH + 8 * q);
      const float4 a = P[0], b = P[1];
      w8[0]=a.x; w8[1]=a.y; w8[2]=a.z; w8[3]=a.w;
      w8[4]=b.x; w8[5]=b.y; w8[6]=b.z; w8[7]=b.w;
    }
    split8_(w8, &aAh[G], &aAl[G]);
    {
      const float4* P = (const float4*)((layer ? Whh1g : Whh0g) + row * HH + 8 * q);
      const float4 a = P[0], b = P[1];
      w8[0]=a.x; w8[1]=a.y; w8[2]=a.z; w8[3]=a.w;
      w8[4]=b.x; w8[5]=b.y; w8[6]=b.z; w8[7]=b.w;
    }
    split8_(w8, &aBh[G], &aBl[G]);
  }

  // ---- biases: biasf[G*4+r] = b[32G + 16*w01 + 4q + r] (goes into acc init) ----
  float biasf[16];
  {
    const float* bi = layer ? bih1 : bih0;
    const float* bh = layer ? bhh1 : bhh0;
    #pragma unroll
    for (int G = 0; G < 4; ++G)
      #pragma unroll
      for (int r = 0; r < 4; ++r) {
        const int rr = G * 32 + w01 * 16 + 4 * q + r;
        biasf[G * 4 + r] = bi[rr] + bh[rr];
      }
  }

  float cst[4] = {0.f, 0.f, 0.f, 0.f};

  float lnc[16];
  float4 xpre0, xpre1;
  const float* xgb = X + (size_t)(b0 + col) * (TT * 8);
  const int tl0 = w01 * 4 + q;   // this lane's staging t-slot

  // ---- prologue: L0 waves stage chunk 0 -> buf 0, prefetch chunk 1 ----
  if (layer == 0) {
    #pragma unroll
    for (int i = 0; i < 8; ++i) { lnc[i] = ln_g[i]; lnc[8 + i] = ln_b[i]; }
    const float4* P = (const float4*)(xgb + tl0 * 8);
    stageX_(P[0], P[1], tl0, col, Xhi[0], Xlo[0], lnc);
    const float4* Q = (const float4*)(xgb + (8 + tl0) * 8);
    xpre0 = Q[0]; xpre1 = Q[1];
  }
  if (layer == 1) {
    // zero h2(-1) = H2[1] slice
    *(uint2*)&H2hi[1][col][ubase] = make_uint2(0, 0);
    *(uint2*)&H2lo[1][col][ubase] = make_uint2(0, 0);
  }
  __syncthreads();

  // ---- t=0 for L0 waves: PA(0) = b0 + Wih0*x(0) ----
  if (layer == 0) {
    f32x4 acc[4];
    #pragma unroll
    for (int G = 0; G < 4; ++G) {
      f32x4 a = { biasf[G*4+0], biasf[G*4+1], biasf[G*4+2], biasf[G*4+3] };
      acc[G] = a;
    }
    const short8 bAh = *(const short8*)&Xhi[0][0][col][0];
    const short8 bAl = *(const short8*)&Xlo[0][0][col][0];
    #pragma unroll
    for (int G = 0; G < 4; ++G) {
      acc[G] = MFMA(aAh[G], bAh, acc[G]);
      acc[G] = MFMA(aAh[G], bAl, acc[G]);
      acc[G] = MFMA(aAl[G], bAh, acc[G]);
    }
    ew4_(acc, cst, &H1hi[0][col][ubase], &H1lo[0][col][ubase]);  // h1(0)
  }
  __syncthreads();

  // ---- main loop: iter j computes PA(j+1) [L0] and PB(j) [L1] ----
  for (int j = 0; j < TT - 1; ++j) {
    const int p = j & 1;  // H1[p]=h1(j), H2[1-p]=h2(j-1); write H1[1-p], H2[p]

    if (layer == 0 && (j & 7) == 6) {
      // stage chunk cn=(j+2)/8 into buf cn&1 (first consumed NEXT iter,
      // after this iter's barrier); prefetch chunk cn+1. Split across both
      // L0 waves: each lane stages one t-slot (tl0).
      const int cn = (j + 2) >> 3;
      stageX_(xpre0, xpre1, tl0, col, Xhi[cn & 1], Xlo[cn & 1], lnc);
      if (cn + 1 < TT / 8) {
        const float4* P = (const float4*)(xgb + ((cn + 1) * 8 + tl0) * 8);
        xpre0 = P[0]; xpre1 = P[1];
      }
    }

    short8 bAh, bAl, bBh, bBl;
    if (layer == 0) {
      const int t1 = j + 1;
      const int xbuf = (t1 >> 3) & 1;
      const int tl = t1 & 7;
      bAh = *(const short8*)&Xhi[xbuf][tl][col][0];
      bAl = *(const short8*)&Xlo[xbuf][tl][col][0];
      bBh = *(const short8*)&H1hi[p][col][8 * q];
      bBl = *(const short8*)&H1lo[p][col][8 * q];
    } else {
      bAh = *(const short8*)&H1hi[p][col][8 * q];
      bAl = *(const short8*)&H1lo[p][col][8 * q];
      bBh = *(const short8*)&H2hi[1 - p][col][8 * q];
      bBl = *(const short8*)&H2lo[1 - p][col][8 * q];
    }

    f32x4 acc[4];
    #pragma unroll
    for (int G = 0; G < 4; ++G) {
      f32x4 a = { biasf[G*4+0], biasf[G*4+1], biasf[G*4+2], biasf[G*4+3] };
      acc[G] = a;
    }
    #pragma unroll
    for (int G = 0; G < 4; ++G) {
      acc[G] = MFMA(aAh[G], bAh, acc[G]);
      acc[G] = MFMA(aAh[G], bAl, acc[G]);
      acc[G] = MFMA(aAl[G], bAh, acc[G]);
      acc[G] = MFMA(aBh[G], bBh, acc[G]);
      acc[G] = MFMA(aBh[G], bBl, acc[G]);
      acc[G] = MFMA(aBl[G], bBh, acc[G]);
    }

    ushort* dhi = layer ? &H2hi[p][col][ubase] : &H1hi[1 - p][col][ubase];
    ushort* dlo = layer ? &H2lo[p][col][ubase] : &H1lo[1 - p][col][ubase];
    ew4_(acc, cst, dhi, dlo);
    __syncthreads();
  }

  // ---- epilogue: PB(511) on L1 waves; h1(511)=H1[1], h2(510)=H2[0] ----
  if (layer == 1) {
    f32x4 acc[4];
    #pragma unroll
    for (int G = 0; G < 4; ++G) {
      f32x4 a = { biasf[G*4+0], biasf[G*4+1], biasf[G*4+2], biasf[G*4+3] };
      acc[G] = a;
    }
    const short8 bAh = *(const short8*)&H1hi[1][col][8 * q];
    const short8 bAl = *(const short8*)&H1lo[1][col][8 * q];
    const short8 bBh = *(const short8*)&H2hi[0][col][8 * q];
    const short8 bBl = *(const short8*)&H2lo[0][col][8 * q];
    #pragma unroll
    for (int G = 0; G < 4; ++G) {
      acc[G] = MFMA(aAh[G], bAh, acc[G]);
      acc[G] = MFMA(aAh[G], bAl, acc[G]);
      acc[G] = MFMA(aAl[G], bAh, acc[G]);
      acc[G] = MFMA(aBh[G], bBh, acc[G]);
      acc[G] = MFMA(aBh[G], bBl, acc[G]);
      acc[G] = MFMA(aBl[G], bBh, acc[G]);
    }
    ew4_(acc, cst, &H2hi[1][col][ubase], &H2lo[1][col][ubase]);  // h2(511)
  }
  __syncthreads();

  // ---- head on wave 0: out[b] = tanh(W2 @ relu(W1 @ h2 + b1) + b2) ----
  if (wv == 0) {
    const int f = lane & 15;   // F1 = 16
    const int bg = lane >> 4;  // 4 batches per lane-group
    float w1r[32];
    {
      const float4* wp = (const float4*)(W1 + f * HH);
      #pragma unroll
      for (int qq = 0; qq < 8; ++qq) {
        const float4 v = wp[qq];
        w1r[4*qq]=v.x; w1r[4*qq+1]=v.y; w1r[4*qq+2]=v.z; w1r[4*qq+3]=v.w;
      }
    }
    const float w2 = W2[f], bb1 = b1[f], bb2 = b2[0];
    #pragma unroll
    for (int s = 0; s < 4; ++s) {
      const int b = bg * 4 + s;
      float a = bb1;
      #pragma unroll
      for (int u = 0; u < HH; ++u) {
        const float h = bf16f_(H2hi[1][b][u]) + bf16f_(H2lo[1][b][u]);
        a = fmaf(w1r[u], h, a);
      }
      float r = fmaxf(a, 0.f) * w2;
      r += __shfl_xor(r, 1);
      r += __shfl_xor(r, 2);
      r += __shfl_xor(r, 4);
      r += __shfl_xor(r, 8);
      if (f == 0) out[b0 + b] = tanhf_(r + bb2);
    }
  }
}

extern "C" void kernel_launch(void* const* d_in, const int* in_sizes, int n_in,
                              void* d_out, int out_size, void* d_ws, size_t ws_size,
                              hipStream_t stream) {
  const float* X     = (const float*)d_in[0];
  const float* ln_g  = (const float*)d_in[1];
  const float* ln_b  = (const float*)d_in[2];
  const float* Wih0g = (const float*)d_in[3];
  const float* Whh0g = (const float*)d_in[4];
  const float* bih0  = (const float*)d_in[5];
  const float* bhh0  = (const float*)d_in[6];
  const float* Wih1g = (const float*)d_in[7];
  const float* Whh1g = (const float*)d_in[8];
  const float* bih1  = (const float*)d_in[9];
  const float* bhh1  = (const float*)d_in[10];
  const float* W1    = (const float*)d_in[11];
  const float* b1    = (const float*)d_in[12];
  const float* W2    = (const float*)d_in[13];
  const float* b2    = (const float*)d_in[14];
  float* out = (float*)d_out;

  const int Bn = in_sizes[0] / (TT * 8);   // 8192
  dim3 grid(Bn / 16), block(256);
  hipLaunchKernelGGL(lstm_mfma, grid, block, 0, stream,
                     X, ln_g, ln_b, Wih0g, Whh0g, bih0, bhh0,
                     Wih1g, Whh1g, bih1, bhh1, W1, b1, W2, b2, out);
}

// Round 4
// 769.958 us; speedup vs baseline: 1.0841x; 1.0376x over previous
//
#include <hip/hip_runtime.h>
#include <hip/hip_bf16.h>

#define TT 512
#define HH 32

typedef __attribute__((ext_vector_type(8))) short short8;
typedef __attribute__((ext_vector_type(4))) float f32x4;
typedef __attribute__((ext_vector_type(2))) float f32x2;

__device__ __forceinline__ float rcpf_(float x) { return __builtin_amdgcn_rcpf(x); }
// 2^x via a single v_exp_f32 (trans pipe).
__device__ __forceinline__ float expv_(float x) {
  float r;
  asm("v_exp_f32 %0, %1" : "=v"(r) : "v"(x));
  return r;
}
__device__ __forceinline__ f32x2 vfma_(f32x2 a, f32x2 b, f32x2 c) {
  return __builtin_elementwise_fma(a, b, c);
}
__device__ __forceinline__ float tanhf_(float z) {  // head only (1 use/block)
  float a = fabsf(z);
  float e = __expf(-2.f * a);
  return copysignf((1.f - e) * rcpf_(1.f + e), z);
}
__device__ __forceinline__ float bf16f_(ushort u) {
  uint b = (uint)u << 16;
  return __uint_as_float(b);
}

// cheap round-to-nearest bf16: add half-ulp then truncate. Exact-residual split.
__device__ __forceinline__ void split8_(const float* w, short8* hi, short8* lo) {
  union { short8 v; ushort u[8]; } H, L;
  #pragma unroll
  for (int i = 0; i < 8; ++i) {
    const uint hb = __float_as_uint(w[i]) + 0x8000u;
    H.u[i] = (ushort)(hb >> 16);
    const float hif = __uint_as_float(hb & 0xffff0000u);
    const uint lb = __float_as_uint(w[i] - hif) + 0x8000u;
    L.u[i] = (ushort)(lb >> 16);
  }
  *hi = H.v; *lo = L.v;
}

// LN one timestep (8 inputs in-lane) + bf16 hi/lo split -> X LDS row
__device__ __forceinline__ void stageX_(float4 va, float4 vb, int tloc, int col,
                                        ushort (*Xhi)[16][8], ushort (*Xlo)[16][8],
                                        const float* lnc) {
  float v[8] = {va.x, va.y, va.z, va.w, vb.x, vb.y, vb.z, vb.w};
  float s = 0.f;
  #pragma unroll
  for (int i = 0; i < 8; ++i) s += v[i];
  const float mu = s * 0.125f;
  float d[8], q2 = 0.f;
  #pragma unroll
  for (int i = 0; i < 8; ++i) { d[i] = v[i] - mu; q2 += d[i] * d[i]; }
  const float inv = __builtin_amdgcn_rsqf(fmaf(q2, 0.125f, 1e-5f));
  float xn[8];
  #pragma unroll
  for (int i = 0; i < 8; ++i) xn[i] = fmaf(d[i] * inv, lnc[i], lnc[8 + i]);
  short8 h8, l8;
  split8_(xn, &h8, &l8);
  *(short8*)&Xhi[tloc][col][0] = h8;
  *(short8*)&Xlo[tloc][col][0] = l8;
}

// Elementwise for 4 units as 2x f32x2 (native vector ops; compiler may form
// v_pk_*_f32 -- semantics guaranteed either way). Preacts arrive as two
// accumulator sets (x-chain incl. bias, h-chain from zero), combined here.
// sig/tanh via 2^x: sig(z)=1/(1+2^(-z*log2e)), tanh(z)=2*sig(2z)-1.
// One rcp per unit-quad of gate denominators (prefix products) and one rcp
// across the 4 units' tanh(c) denominators.
// Gate exp args UNCLAMPED: LN bounds |x|<=2.65, |h|<=1 => |preact|<=11.7 =>
// arg<=33.8, denominator product pp <= 2.7e25 << f32 max. c-args keep
// min(.,30) so the 4-way tail product stays < 2^120.
__device__ __forceinline__ void ew4_(const f32x4* aX, const f32x4* aH, float* cst,
                                     ushort* dhi, ushort* dlo) {
  const f32x2 mC1 = {-1.44269504f, -1.44269504f};   // -log2(e)
  const f32x2 mC2 = {-2.88539008f, -2.88539008f};   // -2*log2(e)
  const f32x2 one2 = {1.f, 1.f};
  const f32x2 two2 = {2.f, 2.f};
  const f32x2 m12  = {-1.f, -1.f};
  f32x2 o_[2], cc[2];
  #pragma unroll
  for (int j = 0; j < 2; ++j) {
    const f32x2 pi = (f32x2){aX[0][2*j], aX[0][2*j+1]} + (f32x2){aH[0][2*j], aH[0][2*j+1]};
    const f32x2 pf = (f32x2){aX[1][2*j], aX[1][2*j+1]} + (f32x2){aH[1][2*j], aH[1][2*j+1]};
    const f32x2 pg = (f32x2){aX[2][2*j], aX[2][2*j+1]} + (f32x2){aH[2][2*j], aH[2][2*j+1]};
    const f32x2 po = (f32x2){aX[3][2*j], aX[3][2*j+1]} + (f32x2){aH[3][2*j], aH[3][2*j+1]};
    const f32x2 ai = pi * mC1, af = pf * mC1;
    const f32x2 ag = pg * mC2, ao = po * mC1;
    const f32x2 ei = {expv_(ai.x), expv_(ai.y)};
    const f32x2 ef = {expv_(af.x), expv_(af.y)};
    const f32x2 eg = {expv_(ag.x), expv_(ag.y)};
    const f32x2 eo = {expv_(ao.x), expv_(ao.y)};
    const f32x2 di = ei + one2, df = ef + one2;
    const f32x2 dg = eg + one2, dq = eo + one2;
    const f32x2 p1 = di * df, p2 = dg * dq;
    const f32x2 pp = p1 * p2;
    const f32x2 rr = {rcpf_(pp.x), rcpf_(pp.y)};
    const f32x2 r1 = rr * p2, r2 = rr * p1;           // 1/p1, 1/p2
    const f32x2 iv = r1 * df, fv = r1 * di;           // sig(i), sig(f)
    const f32x2 gv = vfma_(two2, r2 * dq, m12);       // tanh(g)
    o_[j] = r2 * dg;                                  // sig(o)
    const f32x2 cp = {cst[2*j], cst[2*j+1]};
    const f32x2 c = vfma_(fv, cp, iv * gv);
    cst[2*j] = c.x; cst[2*j+1] = c.y;
    cc[j] = c;
  }
  // tanh(c) for 4 units: clamp args, one shared reciprocal
  const f32x2 ca0 = cc[0] * mC2, ca1 = cc[1] * mC2;
  const f32x2 ee0 = {expv_(fminf(ca0.x, 30.f)), expv_(fminf(ca0.y, 30.f))};
  const f32x2 ee1 = {expv_(fminf(ca1.x, 30.f)), expv_(fminf(ca1.y, 30.f))};
  const f32x2 dd0 = ee0 + one2, dd1 = ee1 + one2;
  const float q1 = dd0.x * dd0.y, q2 = dd1.x * dd1.y;
  const float rq = rcpf_(q1 * q2);
  const float s1 = rq * q2, s2 = rq * q1;      // 1/(d0*d1), 1/(d2*d3)
  const f32x2 th0 = {fmaf(2.f, s1 * dd0.y, -1.f), fmaf(2.f, s1 * dd0.x, -1.f)};
  const f32x2 th1 = {fmaf(2.f, s2 * dd1.y, -1.f), fmaf(2.f, s2 * dd1.x, -1.f)};
  const f32x2 h0 = o_[0] * th0, h1 = o_[1] * th1;
  // bf16 hi/lo split: round-1-proven add-half-ulp/truncate, exact residual
  const float hv[4] = {h0.x, h0.y, h1.x, h1.y};
  uint hp[2], lp[2];
  #pragma unroll
  for (int pr = 0; pr < 2; ++pr) {
    uint h16[2], l16[2];
    #pragma unroll
    for (int s = 0; s < 2; ++s) {
      const float h = hv[pr * 2 + s];
      const uint hb = __float_as_uint(h) + 0x8000u;
      const float hif = __uint_as_float(hb & 0xffff0000u);
      const uint lb = __float_as_uint(h - hif) + 0x8000u;
      h16[s] = hb >> 16;
      l16[s] = lb >> 16;
    }
    hp[pr] = h16[0] | (h16[1] << 16);
    lp[pr] = l16[0] | (l16[1] << 16);
  }
  *(uint2*)dhi = make_uint2(hp[0], hp[1]);
  *(uint2*)dlo = make_uint2(lp[0], lp[1]);
}

#define MFMA(A, B, C) __builtin_amdgcn_mfma_f32_16x16x32_bf16((A), (B), (C), 0, 0, 0)

// 256 threads = 4 waves; 16 batches/block. waves 0,1 = layer0, waves 2,3 = layer1.
// Wave w01 (=wv&1) owns m-tiles {2G+w01}: gate G rows 32G+16*w01+4q+r -> all 4
// gates of units 16*w01+4q+r live in one wave (in-register elementwise).
// Pipeline: iter j computes PA(j+1) (L0 waves) and PB(j) (L1 waves); 1 barrier/t.
// MFMA chains split 3+3: x-part accumulates onto biasv[G] (C operand = pre-built
// bias vector, zero init movs), h-part onto hoisted zerov; combined by vector
// adds in ew4_. Dependent-MFMA critical path ~halved vs single 6-chain.
// X double-buffered by chunk parity; staging split across both L0 waves.
__global__ __launch_bounds__(256, 1) void lstm_mfma(
    const float* __restrict__ X,
    const float* __restrict__ ln_g, const float* __restrict__ ln_b,
    const float* __restrict__ Wih0g, const float* __restrict__ Whh0g,
    const float* __restrict__ bih0, const float* __restrict__ bhh0,
    const float* __restrict__ Wih1g, const float* __restrict__ Whh1g,
    const float* __restrict__ bih1, const float* __restrict__ bhh1,
    const float* __restrict__ W1, const float* __restrict__ b1,
    const float* __restrict__ W2, const float* __restrict__ b2,
    float* __restrict__ out)
{
  __shared__ __align__(16) ushort H1hi[2][16][40], H1lo[2][16][40];
  __shared__ __align__(16) ushort H2hi[2][16][40], H2lo[2][16][40];
  __shared__ __align__(16) ushort Xhi[2][8][16][8], Xlo[2][8][16][8];

  const int tid = threadIdx.x;
  const int wv = tid >> 6;
  const int lane = tid & 63;
  const int q = lane >> 4;       // k-group / D row-group
  const int col = lane & 15;     // batch col (B/D) and A row (m)
  const int layer = wv >> 1;
  const int w01 = wv & 1;
  const int ubase = w01 * 16 + 4 * q;   // first owned unit
  const int b0 = blockIdx.x * 16;

  // ---- A-fragments (weights), once ----
  short8 aAh[4], aAl[4], aBh[4], aBl[4];
  #pragma unroll
  for (int G = 0; G < 4; ++G) {
    const int row = G * 32 + w01 * 16 + col;
    float w8[8];
    if (layer == 0) {
      if (q == 0) {
        const float4 a = ((const float4*)(Wih0g + row * 8))[0];
        const float4 b = ((const float4*)(Wih0g + row * 8))[1];
        w8[0]=a.x; w8[1]=a.y; w8[2]=a.z; w8[3]=a.w;
        w8[4]=b.x; w8[5]=b.y; w8[6]=b.z; w8[7]=b.w;
      } else {
        #pragma unroll
        for (int i = 0; i < 8; ++i) w8[i] = 0.f;
      }
    } else {
      const float4* P = (const float4*)(Wih1g + row * HH + 8 * q);
      const float4 a = P[0], b = P[1];
      w8[0]=a.x; w8[1]=a.y; w8[2]=a.z; w8[3]=a.w;
      w8[4]=b.x; w8[5]=b.y; w8[6]=b.z; w8[7]=b.w;
    }
    split8_(w8, &aAh[G], &aAl[G]);
    {
      const float4* P = (const float4*)((layer ? Whh1g : Whh0g) + row * HH + 8 * q);
      const float4 a = P[0], b = P[1];
      w8[0]=a.x; w8[1]=a.y; w8[2]=a.z; w8[3]=a.w;
      w8[4]=b.x; w8[5]=b.y; w8[6]=b.z; w8[7]=b.w;
    }
    split8_(w8, &aBh[G], &aBl[G]);
  }

  // ---- biases as f32x4 vectors (MFMA C operands): biasv[G][r] ----
  f32x4 biasv[4];
  const f32x4 zerov = {0.f, 0.f, 0.f, 0.f};
  {
    const float* bi = layer ? bih1 : bih0;
    const float* bh = layer ? bhh1 : bhh0;
    #pragma unroll
    for (int G = 0; G < 4; ++G)
      #pragma unroll
      for (int r = 0; r < 4; ++r) {
        const int rr = G * 32 + w01 * 16 + 4 * q + r;
        biasv[G][r] = bi[rr] + bh[rr];
      }
  }

  float cst[4] = {0.f, 0.f, 0.f, 0.f};

  float lnc[16];
  float4 xpre0, xpre1;
  const float* xgb = X + (size_t)(b0 + col) * (TT * 8);
  const int tl0 = w01 * 4 + q;   // this lane's staging t-slot

  // ---- prologue: L0 waves stage chunk 0 -> buf 0, prefetch chunk 1 ----
  if (layer == 0) {
    #pragma unroll
    for (int i = 0; i < 8; ++i) { lnc[i] = ln_g[i]; lnc[8 + i] = ln_b[i]; }
    const float4* P = (const float4*)(xgb + tl0 * 8);
    stageX_(P[0], P[1], tl0, col, Xhi[0], Xlo[0], lnc);
    const float4* Q = (const float4*)(xgb + (8 + tl0) * 8);
    xpre0 = Q[0]; xpre1 = Q[1];
  }
  if (layer == 1) {
    // zero h2(-1) = H2[1] slice
    *(uint2*)&H2hi[1][col][ubase] = make_uint2(0, 0);
    *(uint2*)&H2lo[1][col][ubase] = make_uint2(0, 0);
  }
  __syncthreads();

  // ---- t=0 for L0 waves: PA(0) = b0 + Wih0*x(0) ----
  if (layer == 0) {
    f32x4 accX[4], accH[4];
    const short8 bAh = *(const short8*)&Xhi[0][0][col][0];
    const short8 bAl = *(const short8*)&Xlo[0][0][col][0];
    #pragma unroll
    for (int G = 0; G < 4; ++G) {
      accX[G] = MFMA(aAh[G], bAh, biasv[G]);
      accX[G] = MFMA(aAh[G], bAl, accX[G]);
      accX[G] = MFMA(aAl[G], bAh, accX[G]);
      accH[G] = zerov;
    }
    ew4_(accX, accH, cst, &H1hi[0][col][ubase], &H1lo[0][col][ubase]);  // h1(0)
  }
  __syncthreads();

  // ---- main loop: iter j computes PA(j+1) [L0] and PB(j) [L1] ----
  for (int j = 0; j < TT - 1; ++j) {
    const int p = j & 1;  // H1[p]=h1(j), H2[1-p]=h2(j-1); write H1[1-p], H2[p]

    if (layer == 0 && (j & 7) == 6) {
      // stage chunk cn=(j+2)/8 into buf cn&1 (first consumed NEXT iter,
      // after this iter's barrier); prefetch chunk cn+1. Split across both
      // L0 waves: each lane stages one t-slot (tl0).
      const int cn = (j + 2) >> 3;
      stageX_(xpre0, xpre1, tl0, col, Xhi[cn & 1], Xlo[cn & 1], lnc);
      if (cn + 1 < TT / 8) {
        const float4* P = (const float4*)(xgb + ((cn + 1) * 8 + tl0) * 8);
        xpre0 = P[0]; xpre1 = P[1];
      }
    }

    short8 bAh, bAl, bBh, bBl;
    if (layer == 0) {
      const int t1 = j + 1;
      const int xbuf = (t1 >> 3) & 1;
      const int tl = t1 & 7;
      bAh = *(const short8*)&Xhi[xbuf][tl][col][0];
      bAl = *(const short8*)&Xlo[xbuf][tl][col][0];
      bBh = *(const short8*)&H1hi[p][col][8 * q];
      bBl = *(const short8*)&H1lo[p][col][8 * q];
    } else {
      bAh = *(const short8*)&H1hi[p][col][8 * q];
      bAl = *(const short8*)&H1lo[p][col][8 * q];
      bBh = *(const short8*)&H2hi[1 - p][col][8 * q];
      bBl = *(const short8*)&H2lo[1 - p][col][8 * q];
    }

    // split accumulator chains: x-part (onto bias), h-part (onto zero)
    f32x4 accX[4], accH[4];
    #pragma unroll
    for (int G = 0; G < 4; ++G) accX[G] = MFMA(aAh[G], bAh, biasv[G]);
    #pragma unroll
    for (int G = 0; G < 4; ++G) accH[G] = MFMA(aBh[G], bBh, zerov);
    #pragma unroll
    for (int G = 0; G < 4; ++G) accX[G] = MFMA(aAh[G], bAl, accX[G]);
    #pragma unroll
    for (int G = 0; G < 4; ++G) accH[G] = MFMA(aBh[G], bBl, accH[G]);
    #pragma unroll
    for (int G = 0; G < 4; ++G) accX[G] = MFMA(aAl[G], bAh, accX[G]);
    #pragma unroll
    for (int G = 0; G < 4; ++G) accH[G] = MFMA(aBl[G], bBh, accH[G]);

    ushort* dhi = layer ? &H2hi[p][col][ubase] : &H1hi[1 - p][col][ubase];
    ushort* dlo = layer ? &H2lo[p][col][ubase] : &H1lo[1 - p][col][ubase];
    ew4_(accX, accH, cst, dhi, dlo);
    __syncthreads();
  }

  // ---- epilogue: PB(511) on L1 waves; h1(511)=H1[1], h2(510)=H2[0] ----
  if (layer == 1) {
    f32x4 accX[4], accH[4];
    const short8 bAh = *(const short8*)&H1hi[1][col][8 * q];
    const short8 bAl = *(const short8*)&H1lo[1][col][8 * q];
    const short8 bBh = *(const short8*)&H2hi[0][col][8 * q];
    const short8 bBl = *(const short8*)&H2lo[0][col][8 * q];
    #pragma unroll
    for (int G = 0; G < 4; ++G) {
      accX[G] = MFMA(aAh[G], bAh, biasv[G]);
      accX[G] = MFMA(aAh[G], bAl, accX[G]);
      accX[G] = MFMA(aAl[G], bAh, accX[G]);
      accH[G] = MFMA(aBh[G], bBh, zerov);
      accH[G] = MFMA(aBh[G], bBl, accH[G]);
      accH[G] = MFMA(aBl[G], bBh, accH[G]);
    }
    ew4_(accX, accH, cst, &H2hi[1][col][ubase], &H2lo[1][col][ubase]);  // h2(511)
  }
  __syncthreads();

  // ---- head on wave 0: out[b] = tanh(W2 @ relu(W1 @ h2 + b1) + b2) ----
  if (wv == 0) {
    const int f = lane & 15;   // F1 = 16
    const int bg = lane >> 4;  // 4 batches per lane-group
    float w1r[32];
    {
      const float4* wp = (const float4*)(W1 + f * HH);
      #pragma unroll
      for (int qq = 0; qq < 8; ++qq) {
        const float4 v = wp[qq];
        w1r[4*qq]=v.x; w1r[4*qq+1]=v.y; w1r[4*qq+2]=v.z; w1r[4*qq+3]=v.w;
      }
    }
    const float w2 = W2[f], bb1 = b1[f], bb2 = b2[0];
    #pragma unroll
    for (int s = 0; s < 4; ++s) {
      const int b = bg * 4 + s;
      float a = bb1;
      #pragma unroll
      for (int u = 0; u < HH; ++u) {
        const float h = bf16f_(H2hi[1][b][u]) + bf16f_(H2lo[1][b][u]);
        a = fmaf(w1r[u], h, a);
      }
      float r = fmaxf(a, 0.f) * w2;
      r += __shfl_xor(r, 1);
      r += __shfl_xor(r, 2);
      r += __shfl_xor(r, 4);
      r += __shfl_xor(r, 8);
      if (f == 0) out[b0 + b] = tanhf_(r + bb2);
    }
  }
}

extern "C" void kernel_launch(void* const* d_in, const int* in_sizes, int n_in,
                              void* d_out, int out_size, void* d_ws, size_t ws_size,
                              hipStream_t stream) {
  const float* X     = (const float*)d_in[0];
  const float* ln_g  = (const float*)d_in[1];
  const float* ln_b  = (const float*)d_in[2];
  const float* Wih0g = (const float*)d_in[3];
  const float* Whh0g = (const float*)d_in[4];
  const float* bih0  = (const float*)d_in[5];
  const float* bhh0  = (const float*)d_in[6];
  const float* Wih1g = (const float*)d_in[7];
  const float* Whh1g = (const float*)d_in[8];
  const float* bih1  = (const float*)d_in[9];
  const float* bhh1  = (const float*)d_in[10];
  const float* W1    = (const float*)d_in[11];
  const float* b1    = (const float*)d_in[12];
  const float* W2    = (const float*)d_in[13];
  const float* b2    = (const float*)d_in[14];
  float* out = (float*)d_out;

  const int Bn = in_sizes[0] / (TT * 8);   // 8192
  dim3 grid(Bn / 16), block(256);
  hipLaunchKernelGGL(lstm_mfma, grid, block, 0, stream,
                     X, ln_g, ln_b, Wih0g, Whh0g, bih0, bhh0,
                     Wih1g, Whh1g, bih1, bhh1, W1, b1, W2, b2, out);
}

// Round 5
// 671.502 us; speedup vs baseline: 1.2430x; 1.1466x over previous
//
#include <hip/hip_runtime.h>
#include <hip/hip_bf16.h>

#define TT 512
#define HH 32

typedef __attribute__((ext_vector_type(8))) short short8;
typedef __attribute__((ext_vector_type(4))) float f32x4;
typedef __attribute__((ext_vector_type(2))) float f32x2;

__device__ __forceinline__ float rcpf_(float x) { return __builtin_amdgcn_rcpf(x); }
// 2^x via a single v_exp_f32 (trans pipe).
__device__ __forceinline__ float expv_(float x) {
  float r;
  asm("v_exp_f32 %0, %1" : "=v"(r) : "v"(x));
  return r;
}
__device__ __forceinline__ f32x2 vfma_(f32x2 a, f32x2 b, f32x2 c) {
  return __builtin_elementwise_fma(a, b, c);
}
__device__ __forceinline__ float tanhf_(float z) {  // head only (1 use/block)
  float a = fabsf(z);
  float e = __expf(-2.f * a);
  return copysignf((1.f - e) * rcpf_(1.f + e), z);
}
__device__ __forceinline__ float bf16f_(ushort u) {
  uint b = (uint)u << 16;
  return __uint_as_float(b);
}

// cheap round-to-nearest bf16: add half-ulp then truncate. Exact-residual split.
__device__ __forceinline__ void split8_(const float* w, short8* hi, short8* lo) {
  union { short8 v; ushort u[8]; } H, L;
  #pragma unroll
  for (int i = 0; i < 8; ++i) {
    const uint hb = __float_as_uint(w[i]) + 0x8000u;
    H.u[i] = (ushort)(hb >> 16);
    const float hif = __uint_as_float(hb & 0xffff0000u);
    const uint lb = __float_as_uint(w[i] - hif) + 0x8000u;
    L.u[i] = (ushort)(lb >> 16);
  }
  *hi = H.v; *lo = L.v;
}

// LN one timestep (8 inputs in-lane) + bf16 hi/lo split -> X LDS row
// (X keeps FULL hi/lo precision; only h is stored bf16-only.)
__device__ __forceinline__ void stageX_(float4 va, float4 vb, int tloc, int col,
                                        ushort (*Xhi)[16][8], ushort (*Xlo)[16][8],
                                        const float* lnc) {
  float v[8] = {va.x, va.y, va.z, va.w, vb.x, vb.y, vb.z, vb.w};
  float s = 0.f;
  #pragma unroll
  for (int i = 0; i < 8; ++i) s += v[i];
  const float mu = s * 0.125f;
  float d[8], q2 = 0.f;
  #pragma unroll
  for (int i = 0; i < 8; ++i) { d[i] = v[i] - mu; q2 += d[i] * d[i]; }
  const float inv = __builtin_amdgcn_rsqf(fmaf(q2, 0.125f, 1e-5f));
  float xn[8];
  #pragma unroll
  for (int i = 0; i < 8; ++i) xn[i] = fmaf(d[i] * inv, lnc[i], lnc[8 + i]);
  short8 h8, l8;
  split8_(xn, &h8, &l8);
  *(short8*)&Xhi[tloc][col][0] = h8;
  *(short8*)&Xlo[tloc][col][0] = l8;
}

// Elementwise for 4 units as 2x f32x2. Preacts arrive as two accumulator sets
// (x-chain incl. bias, h-chain from zero), combined here.
// sig/tanh via 2^x: sig(z)=1/(1+2^(-z*log2e)), tanh(z)=2*sig(2z)-1.
// One rcp per unit-quad of gate denominators (prefix products) and one rcp
// across the 4 units' tanh(c) denominators.
// Gate exp args UNCLAMPED: LN bounds |x|<=2.65, |h|<=1 => |preact|<=11.7 =>
// arg<=33.8, denominator product pp <= 2.7e25 << f32 max. c-args keep
// min(.,30) so the 4-way tail product stays < 2^120.
// h is stored bf16-only (RNE via add-half-ulp): saves the lo split, the lo
// write, and 1 MFMA per consuming chain. Error budget: h rel err 2^-9 ->
// preact err ~3e-4, damped by gate slopes; predicted out err ~2-5e-4 < thr.
__device__ __forceinline__ void ew4_(const f32x4* aX, const f32x4* aH, float* cst,
                                     ushort* dhi) {
  const f32x2 mC1 = {-1.44269504f, -1.44269504f};   // -log2(e)
  const f32x2 mC2 = {-2.88539008f, -2.88539008f};   // -2*log2(e)
  const f32x2 one2 = {1.f, 1.f};
  const f32x2 two2 = {2.f, 2.f};
  const f32x2 m12  = {-1.f, -1.f};
  f32x2 o_[2], cc[2];
  #pragma unroll
  for (int j = 0; j < 2; ++j) {
    const f32x2 pi = (f32x2){aX[0][2*j], aX[0][2*j+1]} + (f32x2){aH[0][2*j], aH[0][2*j+1]};
    const f32x2 pf = (f32x2){aX[1][2*j], aX[1][2*j+1]} + (f32x2){aH[1][2*j], aH[1][2*j+1]};
    const f32x2 pg = (f32x2){aX[2][2*j], aX[2][2*j+1]} + (f32x2){aH[2][2*j], aH[2][2*j+1]};
    const f32x2 po = (f32x2){aX[3][2*j], aX[3][2*j+1]} + (f32x2){aH[3][2*j], aH[3][2*j+1]};
    const f32x2 ai = pi * mC1, af = pf * mC1;
    const f32x2 ag = pg * mC2, ao = po * mC1;
    const f32x2 ei = {expv_(ai.x), expv_(ai.y)};
    const f32x2 ef = {expv_(af.x), expv_(af.y)};
    const f32x2 eg = {expv_(ag.x), expv_(ag.y)};
    const f32x2 eo = {expv_(ao.x), expv_(ao.y)};
    const f32x2 di = ei + one2, df = ef + one2;
    const f32x2 dg = eg + one2, dq = eo + one2;
    const f32x2 p1 = di * df, p2 = dg * dq;
    const f32x2 pp = p1 * p2;
    const f32x2 rr = {rcpf_(pp.x), rcpf_(pp.y)};
    const f32x2 r1 = rr * p2, r2 = rr * p1;           // 1/p1, 1/p2
    const f32x2 iv = r1 * df, fv = r1 * di;           // sig(i), sig(f)
    const f32x2 gv = vfma_(two2, r2 * dq, m12);       // tanh(g)
    o_[j] = r2 * dg;                                  // sig(o)
    const f32x2 cp = {cst[2*j], cst[2*j+1]};
    const f32x2 c = vfma_(fv, cp, iv * gv);
    cst[2*j] = c.x; cst[2*j+1] = c.y;
    cc[j] = c;
  }
  // tanh(c) for 4 units: clamp args, one shared reciprocal
  const f32x2 ca0 = cc[0] * mC2, ca1 = cc[1] * mC2;
  const f32x2 ee0 = {expv_(fminf(ca0.x, 30.f)), expv_(fminf(ca0.y, 30.f))};
  const f32x2 ee1 = {expv_(fminf(ca1.x, 30.f)), expv_(fminf(ca1.y, 30.f))};
  const f32x2 dd0 = ee0 + one2, dd1 = ee1 + one2;
  const float q1 = dd0.x * dd0.y, q2 = dd1.x * dd1.y;
  const float rq = rcpf_(q1 * q2);
  const float s1 = rq * q2, s2 = rq * q1;      // 1/(d0*d1), 1/(d2*d3)
  const f32x2 th0 = {fmaf(2.f, s1 * dd0.y, -1.f), fmaf(2.f, s1 * dd0.x, -1.f)};
  const f32x2 th1 = {fmaf(2.f, s2 * dd1.y, -1.f), fmaf(2.f, s2 * dd1.x, -1.f)};
  const f32x2 h0 = o_[0] * th0, h1 = o_[1] * th1;
  // bf16 pack (round-to-nearest via add-half-ulp), hi only
  const float hv[4] = {h0.x, h0.y, h1.x, h1.y};
  uint hp[2];
  #pragma unroll
  for (int pr = 0; pr < 2; ++pr) {
    const uint b0 = (__float_as_uint(hv[pr*2+0]) + 0x8000u) >> 16;
    const uint b1 = (__float_as_uint(hv[pr*2+1]) + 0x8000u) >> 16;
    hp[pr] = b0 | (b1 << 16);
  }
  *(uint2*)dhi = make_uint2(hp[0], hp[1]);
}

#define MFMA(A, B, C) __builtin_amdgcn_mfma_f32_16x16x32_bf16((A), (B), (C), 0, 0, 0)

// 256 threads = 4 waves; 16 batches/block. waves 0,1 = layer0, waves 2,3 = layer1.
// Wave w01 (=wv&1) owns m-tiles {2G+w01}: gate G rows 32G+16*w01+4q+r -> all 4
// gates of units 16*w01+4q+r live in one wave (in-register elementwise).
// Pipeline: iter j computes PA(j+1) (L0 waves) and PB(j) (L1 waves); 1 barrier/t.
// h is bf16-only in LDS (no lo residual): L0 h-part 2 MFMAs, L1 x-part 2,
// L1 h-part 2 (weights keep hi/lo; X keeps hi/lo).
// MFMA chains split: x-part accumulates onto biasv[G] (C operand), h-part onto
// hoisted zerov; combined by vector adds in ew4_.
// X double-buffered by chunk parity; staging split across both L0 waves.
__global__ __launch_bounds__(256, 1) void lstm_mfma(
    const float* __restrict__ X,
    const float* __restrict__ ln_g, const float* __restrict__ ln_b,
    const float* __restrict__ Wih0g, const float* __restrict__ Whh0g,
    const float* __restrict__ bih0, const float* __restrict__ bhh0,
    const float* __restrict__ Wih1g, const float* __restrict__ Whh1g,
    const float* __restrict__ bih1, const float* __restrict__ bhh1,
    const float* __restrict__ W1, const float* __restrict__ b1,
    const float* __restrict__ W2, const float* __restrict__ b2,
    float* __restrict__ out)
{
  __shared__ __align__(16) ushort H1hi[2][16][40];
  __shared__ __align__(16) ushort H2hi[2][16][40];
  __shared__ __align__(16) ushort Xhi[2][8][16][8], Xlo[2][8][16][8];

  const int tid = threadIdx.x;
  const int wv = tid >> 6;
  const int lane = tid & 63;
  const int q = lane >> 4;       // k-group / D row-group
  const int col = lane & 15;     // batch col (B/D) and A row (m)
  const int layer = wv >> 1;
  const int w01 = wv & 1;
  const int ubase = w01 * 16 + 4 * q;   // first owned unit
  const int b0 = blockIdx.x * 16;

  // ---- A-fragments (weights), once ----
  short8 aAh[4], aAl[4], aBh[4], aBl[4];
  #pragma unroll
  for (int G = 0; G < 4; ++G) {
    const int row = G * 32 + w01 * 16 + col;
    float w8[8];
    if (layer == 0) {
      if (q == 0) {
        const float4 a = ((const float4*)(Wih0g + row * 8))[0];
        const float4 b = ((const float4*)(Wih0g + row * 8))[1];
        w8[0]=a.x; w8[1]=a.y; w8[2]=a.z; w8[3]=a.w;
        w8[4]=b.x; w8[5]=b.y; w8[6]=b.z; w8[7]=b.w;
      } else {
        #pragma unroll
        for (int i = 0; i < 8; ++i) w8[i] = 0.f;
      }
    } else {
      const float4* P = (const float4*)(Wih1g + row * HH + 8 * q);
      const float4 a = P[0], b = P[1];
      w8[0]=a.x; w8[1]=a.y; w8[2]=a.z; w8[3]=a.w;
      w8[4]=b.x; w8[5]=b.y; w8[6]=b.z; w8[7]=b.w;
    }
    split8_(w8, &aAh[G], &aAl[G]);
    {
      const float4* P = (const float4*)((layer ? Whh1g : Whh0g) + row * HH + 8 * q);
      const float4 a = P[0], b = P[1];
      w8[0]=a.x; w8[1]=a.y; w8[2]=a.z; w8[3]=a.w;
      w8[4]=b.x; w8[5]=b.y; w8[6]=b.z; w8[7]=b.w;
    }
    split8_(w8, &aBh[G], &aBl[G]);
  }

  // ---- biases as f32x4 vectors (MFMA C operands): biasv[G][r] ----
  f32x4 biasv[4];
  const f32x4 zerov = {0.f, 0.f, 0.f, 0.f};
  {
    const float* bi = layer ? bih1 : bih0;
    const float* bh = layer ? bhh1 : bhh0;
    #pragma unroll
    for (int G = 0; G < 4; ++G)
      #pragma unroll
      for (int r = 0; r < 4; ++r) {
        const int rr = G * 32 + w01 * 16 + 4 * q + r;
        biasv[G][r] = bi[rr] + bh[rr];
      }
  }

  float cst[4] = {0.f, 0.f, 0.f, 0.f};

  float lnc[16];
  float4 xpre0, xpre1;
  const float* xgb = X + (size_t)(b0 + col) * (TT * 8);
  const int tl0 = w01 * 4 + q;   // this lane's staging t-slot

  // ---- prologue: L0 waves stage chunk 0 -> buf 0, prefetch chunk 1 ----
  if (layer == 0) {
    #pragma unroll
    for (int i = 0; i < 8; ++i) { lnc[i] = ln_g[i]; lnc[8 + i] = ln_b[i]; }
    const float4* P = (const float4*)(xgb + tl0 * 8);
    stageX_(P[0], P[1], tl0, col, Xhi[0], Xlo[0], lnc);
    const float4* Q = (const float4*)(xgb + (8 + tl0) * 8);
    xpre0 = Q[0]; xpre1 = Q[1];
  }
  if (layer == 1) {
    // zero h2(-1) = H2[1] slice
    *(uint2*)&H2hi[1][col][ubase] = make_uint2(0, 0);
  }
  __syncthreads();

  // ---- t=0 for L0 waves: PA(0) = b0 + Wih0*x(0) ----
  if (layer == 0) {
    f32x4 accX[4], accH[4];
    const short8 bAh = *(const short8*)&Xhi[0][0][col][0];
    const short8 bAl = *(const short8*)&Xlo[0][0][col][0];
    #pragma unroll
    for (int G = 0; G < 4; ++G) {
      accX[G] = MFMA(aAh[G], bAh, biasv[G]);
      accX[G] = MFMA(aAh[G], bAl, accX[G]);
      accX[G] = MFMA(aAl[G], bAh, accX[G]);
      accH[G] = zerov;
    }
    ew4_(accX, accH, cst, &H1hi[0][col][ubase]);  // h1(0)
  }
  __syncthreads();

  // ---- main loop: iter j computes PA(j+1) [L0] and PB(j) [L1] ----
  #pragma unroll 2
  for (int j = 0; j < TT - 1; ++j) {
    const int p = j & 1;  // H1[p]=h1(j), H2[1-p]=h2(j-1); write H1[1-p], H2[p]

    if (layer == 0 && (j & 7) == 6) {
      // stage chunk cn=(j+2)/8 into buf cn&1 (first consumed NEXT iter,
      // after this iter's barrier); prefetch chunk cn+1. Split across both
      // L0 waves: each lane stages one t-slot (tl0).
      const int cn = (j + 2) >> 3;
      stageX_(xpre0, xpre1, tl0, col, Xhi[cn & 1], Xlo[cn & 1], lnc);
      if (cn + 1 < TT / 8) {
        const float4* P = (const float4*)(xgb + ((cn + 1) * 8 + tl0) * 8);
        xpre0 = P[0]; xpre1 = P[1];
      }
    }

    f32x4 accX[4], accH[4];
    if (layer == 0) {
      const int t1 = j + 1;
      const int xbuf = (t1 >> 3) & 1;
      const int tl = t1 & 7;
      const short8 bAh = *(const short8*)&Xhi[xbuf][tl][col][0];
      const short8 bAl = *(const short8*)&Xlo[xbuf][tl][col][0];
      const short8 bBh = *(const short8*)&H1hi[p][col][8 * q];
      #pragma unroll
      for (int G = 0; G < 4; ++G) accX[G] = MFMA(aAh[G], bAh, biasv[G]);
      #pragma unroll
      for (int G = 0; G < 4; ++G) accH[G] = MFMA(aBh[G], bBh, zerov);
      #pragma unroll
      for (int G = 0; G < 4; ++G) accX[G] = MFMA(aAh[G], bAl, accX[G]);
      #pragma unroll
      for (int G = 0; G < 4; ++G) accX[G] = MFMA(aAl[G], bAh, accX[G]);
      #pragma unroll
      for (int G = 0; G < 4; ++G) accH[G] = MFMA(aBl[G], bBh, accH[G]);
    } else {
      const short8 bAh = *(const short8*)&H1hi[p][col][8 * q];
      const short8 bBh = *(const short8*)&H2hi[1 - p][col][8 * q];
      #pragma unroll
      for (int G = 0; G < 4; ++G) accX[G] = MFMA(aAh[G], bAh, biasv[G]);
      #pragma unroll
      for (int G = 0; G < 4; ++G) accH[G] = MFMA(aBh[G], bBh, zerov);
      #pragma unroll
      for (int G = 0; G < 4; ++G) accX[G] = MFMA(aAl[G], bAh, accX[G]);
      #pragma unroll
      for (int G = 0; G < 4; ++G) accH[G] = MFMA(aBl[G], bBh, accH[G]);
    }

    ushort* dhi = layer ? &H2hi[p][col][ubase] : &H1hi[1 - p][col][ubase];
    ew4_(accX, accH, cst, dhi);
    __syncthreads();
  }

  // ---- epilogue: PB(511) on L1 waves; h1(511)=H1[1], h2(510)=H2[0] ----
  if (layer == 1) {
    f32x4 accX[4], accH[4];
    const short8 bAh = *(const short8*)&H1hi[1][col][8 * q];
    const short8 bBh = *(const short8*)&H2hi[0][col][8 * q];
    #pragma unroll
    for (int G = 0; G < 4; ++G) {
      accX[G] = MFMA(aAh[G], bAh, biasv[G]);
      accX[G] = MFMA(aAl[G], bAh, accX[G]);
      accH[G] = MFMA(aBh[G], bBh, zerov);
      accH[G] = MFMA(aBl[G], bBh, accH[G]);
    }
    ew4_(accX, accH, cst, &H2hi[1][col][ubase]);  // h2(511)
  }
  __syncthreads();

  // ---- head on wave 0: out[b] = tanh(W2 @ relu(W1 @ h2 + b1) + b2) ----
  if (wv == 0) {
    const int f = lane & 15;   // F1 = 16
    const int bg = lane >> 4;  // 4 batches per lane-group
    float w1r[32];
    {
      const float4* wp = (const float4*)(W1 + f * HH);
      #pragma unroll
      for (int qq = 0; qq < 8; ++qq) {
        const float4 v = wp[qq];
        w1r[4*qq]=v.x; w1r[4*qq+1]=v.y; w1r[4*qq+2]=v.z; w1r[4*qq+3]=v.w;
      }
    }
    const float w2 = W2[f], bb1 = b1[f], bb2 = b2[0];
    #pragma unroll
    for (int s = 0; s < 4; ++s) {
      const int b = bg * 4 + s;
      float a = bb1;
      #pragma unroll
      for (int u = 0; u < HH; ++u) {
        const float h = bf16f_(H2hi[1][b][u]);
        a = fmaf(w1r[u], h, a);
      }
      float r = fmaxf(a, 0.f) * w2;
      r += __shfl_xor(r, 1);
      r += __shfl_xor(r, 2);
      r += __shfl_xor(r, 4);
      r += __shfl_xor(r, 8);
      if (f == 0) out[b0 + b] = tanhf_(r + bb2);
    }
  }
}

extern "C" void kernel_launch(void* const* d_in, const int* in_sizes, int n_in,
                              void* d_out, int out_size, void* d_ws, size_t ws_size,
                              hipStream_t stream) {
  const float* X     = (const float*)d_in[0];
  const float* ln_g  = (const float*)d_in[1];
  const float* ln_b  = (const float*)d_in[2];
  const float* Wih0g = (const float*)d_in[3];
  const float* Whh0g = (const float*)d_in[4];
  const float* bih0  = (const float*)d_in[5];
  const float* bhh0  = (const float*)d_in[6];
  const float* Wih1g = (const float*)d_in[7];
  const float* Whh1g = (const float*)d_in[8];
  const float* bih1  = (const float*)d_in[9];
  const float* bhh1  = (const float*)d_in[10];
  const float* W1    = (const float*)d_in[11];
  const float* b1    = (const float*)d_in[12];
  const float* W2    = (const float*)d_in[13];
  const float* b2    = (const float*)d_in[14];
  float* out = (float*)d_out;

  const int Bn = in_sizes[0] / (TT * 8);   // 8192
  dim3 grid(Bn / 16), block(256);
  hipLaunchKernelGGL(lstm_mfma, grid, block, 0, stream,
                     X, ln_g, ln_b, Wih0g, Whh0g, bih0, bhh0,
                     Wih1g, Whh1g, bih1, bhh1, W1, b1, W2, b2, out);
}

// Round 9
// 648.149 us; speedup vs baseline: 1.2878x; 1.0360x over previous
//
#include <hip/hip_runtime.h>
#include <hip/hip_bf16.h>

#define TT 512
#define HH 32

typedef __attribute__((ext_vector_type(8))) short short8;
typedef __attribute__((ext_vector_type(4))) float f32x4;
typedef __attribute__((ext_vector_type(2))) float f32x2;

__device__ __forceinline__ float rcpf_(float x) { return __builtin_amdgcn_rcpf(x); }
// 2^x via a single v_exp_f32 (trans pipe).
__device__ __forceinline__ float expv_(float x) {
  float r;
  asm("v_exp_f32 %0, %1" : "=v"(r) : "v"(x));
  return r;
}
__device__ __forceinline__ f32x2 vfma_(f32x2 a, f32x2 b, f32x2 c) {
  return __builtin_elementwise_fma(a, b, c);
}
__device__ __forceinline__ float tanhf_(float z) {  // head only (1 use/block)
  float a = fabsf(z);
  float e = __expf(-2.f * a);
  return copysignf((1.f - e) * rcpf_(1.f + e), z);
}
__device__ __forceinline__ float bf16f_(ushort u) {
  uint b = (uint)u << 16;
  return __uint_as_float(b);
}

// cheap round-to-nearest bf16: add half-ulp then truncate. Exact-residual split.
__device__ __forceinline__ void split8_(const float* w, short8* hi, short8* lo) {
  union { short8 v; ushort u[8]; } H, L;
  #pragma unroll
  for (int i = 0; i < 8; ++i) {
    const uint hb = __float_as_uint(w[i]) + 0x8000u;
    H.u[i] = (ushort)(hb >> 16);
    const float hif = __uint_as_float(hb & 0xffff0000u);
    const uint lb = __float_as_uint(w[i] - hif) + 0x8000u;
    L.u[i] = (ushort)(lb >> 16);
  }
  *hi = H.v; *lo = L.v;
}

// LN one timestep (8 inputs in-lane) + bf16 hi/lo split -> X LDS row
// (X keeps FULL hi/lo precision; only h is stored bf16-only.)
__device__ __forceinline__ void stageX_(float4 va, float4 vb, int tloc, int col,
                                        ushort (*Xhi)[16][8], ushort (*Xlo)[16][8],
                                        const float* lnc) {
  float v[8] = {va.x, va.y, va.z, va.w, vb.x, vb.y, vb.z, vb.w};
  float s = 0.f;
  #pragma unroll
  for (int i = 0; i < 8; ++i) s += v[i];
  const float mu = s * 0.125f;
  float d[8], q2 = 0.f;
  #pragma unroll
  for (int i = 0; i < 8; ++i) { d[i] = v[i] - mu; q2 += d[i] * d[i]; }
  const float inv = __builtin_amdgcn_rsqf(fmaf(q2, 0.125f, 1e-5f));
  float xn[8];
  #pragma unroll
  for (int i = 0; i < 8; ++i) xn[i] = fmaf(d[i] * inv, lnc[i], lnc[8 + i]);
  short8 h8, l8;
  split8_(xn, &h8, &l8);
  *(short8*)&Xhi[tloc][col][0] = h8;
  *(short8*)&Xlo[tloc][col][0] = l8;
}

// Elementwise for 4 units as 2x f32x2 (NATIVE vector ops -- the r5-proven
// form; pk-f32 inline asm is abandoned after 3 failed encoding experiments).
// WEIGHTS/BIASES ARE PRE-SCALED by -log2e (gates i,f,o) / -2*log2e (gate g),
// so MFMA accumulators arrive exp2-ready: ei=2^(pi)=e^{-z_i}, eg=e^{-2 z_g}.
//   sig(z) = 1/(1+e^{-z}), tanh(z) = 2*sig(2z)-1.
// One rcp per unit-pair of gate denominators (prefix products) and one rcp
// across the 4 units' tanh(c) denominators.
// Gate exp args UNCLAMPED: |preact|<=11.7 => arg<=33.8, denominator product
// pp <= 2.7e25 << f32 max. c-args keep min(.,30).
// h is stored bf16-only (RNE via add-half-ulp; proven r5, absmax 2.4e-4).
__device__ __forceinline__ void ew4_(const f32x4* aX, const f32x4* aH, float* cst,
                                     ushort* dhi) {
  const f32x2 mC2 = {-2.88539008f, -2.88539008f};   // -2*log2(e), tail only
  const f32x2 one2 = {1.f, 1.f};
  const f32x2 two2 = {2.f, 2.f};
  const f32x2 m12  = {-1.f, -1.f};
  f32x2 o_[2], cc[2];
  #pragma unroll
  for (int j = 0; j < 2; ++j) {
    // pre-scaled preacts (already *-log2e / *-2log2e)
    const f32x2 pi = (f32x2){aX[0][2*j], aX[0][2*j+1]} + (f32x2){aH[0][2*j], aH[0][2*j+1]};
    const f32x2 pf = (f32x2){aX[1][2*j], aX[1][2*j+1]} + (f32x2){aH[1][2*j], aH[1][2*j+1]};
    const f32x2 pg = (f32x2){aX[2][2*j], aX[2][2*j+1]} + (f32x2){aH[2][2*j], aH[2][2*j+1]};
    const f32x2 po = (f32x2){aX[3][2*j], aX[3][2*j+1]} + (f32x2){aH[3][2*j], aH[3][2*j+1]};
    const f32x2 ei = {expv_(pi.x), expv_(pi.y)};
    const f32x2 ef = {expv_(pf.x), expv_(pf.y)};
    const f32x2 eg = {expv_(pg.x), expv_(pg.y)};
    const f32x2 eo = {expv_(po.x), expv_(po.y)};
    const f32x2 di = ei + one2, df = ef + one2;
    const f32x2 dg = eg + one2, dq = eo + one2;
    const f32x2 p1 = di * df, p2 = dg * dq;
    const f32x2 pp = p1 * p2;
    const f32x2 rr = {rcpf_(pp.x), rcpf_(pp.y)};
    const f32x2 r1 = rr * p2, r2 = rr * p1;           // 1/p1, 1/p2
    const f32x2 iv = r1 * df, fv = r1 * di;           // sig(i), sig(f)
    const f32x2 gv = vfma_(two2, r2 * dq, m12);       // tanh(g)
    o_[j] = r2 * dg;                                  // sig(o)
    const f32x2 cp = {cst[2*j], cst[2*j+1]};
    const f32x2 c = vfma_(fv, cp, iv * gv);
    cst[2*j] = c.x; cst[2*j+1] = c.y;
    cc[j] = c;
  }
  // tanh(c) for 4 units: clamp args, one shared reciprocal
  const f32x2 ca0 = cc[0] * mC2, ca1 = cc[1] * mC2;
  const f32x2 ee0 = {expv_(fminf(ca0.x, 30.f)), expv_(fminf(ca0.y, 30.f))};
  const f32x2 ee1 = {expv_(fminf(ca1.x, 30.f)), expv_(fminf(ca1.y, 30.f))};
  const f32x2 dd0 = ee0 + one2, dd1 = ee1 + one2;
  const float q1 = dd0.x * dd0.y, q2 = dd1.x * dd1.y;
  const float rq = rcpf_(q1 * q2);
  const float s1 = rq * q2, s2 = rq * q1;      // 1/(d0*d1), 1/(d2*d3)
  const f32x2 th0 = {fmaf(2.f, s1 * dd0.y, -1.f), fmaf(2.f, s1 * dd0.x, -1.f)};
  const f32x2 th1 = {fmaf(2.f, s2 * dd1.y, -1.f), fmaf(2.f, s2 * dd1.x, -1.f)};
  const f32x2 h0 = o_[0] * th0, h1 = o_[1] * th1;
  // bf16 pack (round-to-nearest via add-half-ulp), hi only -- proven path
  const float hv[4] = {h0.x, h0.y, h1.x, h1.y};
  uint hp[2];
  #pragma unroll
  for (int pr = 0; pr < 2; ++pr) {
    const uint b0 = (__float_as_uint(hv[pr*2+0]) + 0x8000u) >> 16;
    const uint b1 = (__float_as_uint(hv[pr*2+1]) + 0x8000u) >> 16;
    hp[pr] = b0 | (b1 << 16);
  }
  *(uint2*)dhi = make_uint2(hp[0], hp[1]);
}

#define MFMA(A, B, C) __builtin_amdgcn_mfma_f32_16x16x32_bf16((A), (B), (C), 0, 0, 0)

// 256 threads = 4 waves; 16 batches/block. waves 0,1 = layer0, waves 2,3 = layer1.
// Wave w01 (=wv&1) owns m-tiles {2G+w01}: gate G rows 32G+16*w01+4q+r -> all 4
// gates of units 16*w01+4q+r live in one wave (in-register elementwise).
// Pipeline: iter j computes PA(j+1) (L0 waves) and PB(j) (L1 waves); 1 barrier/t.
// h is bf16-only in LDS (no lo residual). Weights/biases pre-scaled by
// -log2e (i,f,o) / -2log2e (g) so MFMA emits exp2-ready gate arguments.
// MFMA chains split: x-part accumulates onto biasv[G] (C operand), h-part onto
// hoisted zerov; combined by vector adds in ew4_.
// X double-buffered by chunk parity; staging split across both L0 waves.
// s_setprio(1) around the MFMA cluster (2 independent blocks/CU drift in phase).
__global__ __launch_bounds__(256, 1) void lstm_mfma(
    const float* __restrict__ X,
    const float* __restrict__ ln_g, const float* __restrict__ ln_b,
    const float* __restrict__ Wih0g, const float* __restrict__ Whh0g,
    const float* __restrict__ bih0, const float* __restrict__ bhh0,
    const float* __restrict__ Wih1g, const float* __restrict__ Whh1g,
    const float* __restrict__ bih1, const float* __restrict__ bhh1,
    const float* __restrict__ W1, const float* __restrict__ b1,
    const float* __restrict__ W2, const float* __restrict__ b2,
    float* __restrict__ out)
{
  __shared__ __align__(16) ushort H1hi[2][16][40];
  __shared__ __align__(16) ushort H2hi[2][16][40];
  __shared__ __align__(16) ushort Xhi[2][8][16][8], Xlo[2][8][16][8];

  const int tid = threadIdx.x;
  const int wv = tid >> 6;
  const int lane = tid & 63;
  const int q = lane >> 4;       // k-group / D row-group
  const int col = lane & 15;     // batch col (B/D) and A row (m)
  const int layer = wv >> 1;
  const int w01 = wv & 1;
  const int ubase = w01 * 16 + 4 * q;   // first owned unit
  const int b0 = blockIdx.x * 16;

  // ---- A-fragments (weights), once; pre-scaled per gate ----
  short8 aAh[4], aAl[4], aBh[4], aBl[4];
  #pragma unroll
  for (int G = 0; G < 4; ++G) {
    // gate scale: i,f,o -> -log2e ; g (G==2) -> -2*log2e
    const float sc = (G == 2) ? -2.88539008f : -1.44269504f;
    const int row = G * 32 + w01 * 16 + col;
    float w8[8];
    if (layer == 0) {
      if (q == 0) {
        const float4 a = ((const float4*)(Wih0g + row * 8))[0];
        const float4 b = ((const float4*)(Wih0g + row * 8))[1];
        w8[0]=a.x; w8[1]=a.y; w8[2]=a.z; w8[3]=a.w;
        w8[4]=b.x; w8[5]=b.y; w8[6]=b.z; w8[7]=b.w;
      } else {
        #pragma unroll
        for (int i = 0; i < 8; ++i) w8[i] = 0.f;
      }
    } else {
      const float4* P = (const float4*)(Wih1g + row * HH + 8 * q);
      const float4 a = P[0], b = P[1];
      w8[0]=a.x; w8[1]=a.y; w8[2]=a.z; w8[3]=a.w;
      w8[4]=b.x; w8[5]=b.y; w8[6]=b.z; w8[7]=b.w;
    }
    #pragma unroll
    for (int i = 0; i < 8; ++i) w8[i] *= sc;
    split8_(w8, &aAh[G], &aAl[G]);
    {
      const float4* P = (const float4*)((layer ? Whh1g : Whh0g) + row * HH + 8 * q);
      const float4 a = P[0], b = P[1];
      w8[0]=a.x; w8[1]=a.y; w8[2]=a.z; w8[3]=a.w;
      w8[4]=b.x; w8[5]=b.y; w8[6]=b.z; w8[7]=b.w;
    }
    #pragma unroll
    for (int i = 0; i < 8; ++i) w8[i] *= sc;
    split8_(w8, &aBh[G], &aBl[G]);
  }

  // ---- biases as f32x4 vectors (MFMA C operands), pre-scaled ----
  f32x4 biasv[4];
  const f32x4 zerov = {0.f, 0.f, 0.f, 0.f};
  {
    const float* bi = layer ? bih1 : bih0;
    const float* bh = layer ? bhh1 : bhh0;
    #pragma unroll
    for (int G = 0; G < 4; ++G) {
      const float sc = (G == 2) ? -2.88539008f : -1.44269504f;
      #pragma unroll
      for (int r = 0; r < 4; ++r) {
        const int rr = G * 32 + w01 * 16 + 4 * q + r;
        biasv[G][r] = (bi[rr] + bh[rr]) * sc;
      }
    }
  }

  float cst[4] = {0.f, 0.f, 0.f, 0.f};

  float lnc[16];
  float4 xpre0, xpre1;
  const float* xgb = X + (size_t)(b0 + col) * (TT * 8);
  const int tl0 = w01 * 4 + q;   // this lane's staging t-slot

  // ---- prologue: L0 waves stage chunk 0 -> buf 0, prefetch chunk 1 ----
  if (layer == 0) {
    #pragma unroll
    for (int i = 0; i < 8; ++i) { lnc[i] = ln_g[i]; lnc[8 + i] = ln_b[i]; }
    const float4* P = (const float4*)(xgb + tl0 * 8);
    stageX_(P[0], P[1], tl0, col, Xhi[0], Xlo[0], lnc);
    const float4* Q = (const float4*)(xgb + (8 + tl0) * 8);
    xpre0 = Q[0]; xpre1 = Q[1];
  }
  if (layer == 1) {
    // zero h2(-1) = H2[1] slice
    *(uint2*)&H2hi[1][col][ubase] = make_uint2(0, 0);
  }
  __syncthreads();

  // ---- t=0 for L0 waves: PA(0) = b0 + Wih0*x(0) (scaled) ----
  if (layer == 0) {
    f32x4 accX[4], accH[4];
    const short8 bAh = *(const short8*)&Xhi[0][0][col][0];
    const short8 bAl = *(const short8*)&Xlo[0][0][col][0];
    #pragma unroll
    for (int G = 0; G < 4; ++G) {
      accX[G] = MFMA(aAh[G], bAh, biasv[G]);
      accX[G] = MFMA(aAh[G], bAl, accX[G]);
      accX[G] = MFMA(aAl[G], bAh, accX[G]);
      accH[G] = zerov;
    }
    ew4_(accX, accH, cst, &H1hi[0][col][ubase]);  // h1(0)
  }
  __syncthreads();

  // ---- main loop: iter j computes PA(j+1) [L0] and PB(j) [L1] ----
  #pragma unroll 2
  for (int j = 0; j < TT - 1; ++j) {
    const int p = j & 1;  // H1[p]=h1(j), H2[1-p]=h2(j-1); write H1[1-p], H2[p]

    if (layer == 0 && (j & 7) == 6) {
      // stage chunk cn=(j+2)/8 into buf cn&1 (first consumed NEXT iter,
      // after this iter's barrier); prefetch chunk cn+1. Split across both
      // L0 waves: each lane stages one t-slot (tl0).
      const int cn = (j + 2) >> 3;
      stageX_(xpre0, xpre1, tl0, col, Xhi[cn & 1], Xlo[cn & 1], lnc);
      if (cn + 1 < TT / 8) {
        const float4* P = (const float4*)(xgb + ((cn + 1) * 8 + tl0) * 8);
        xpre0 = P[0]; xpre1 = P[1];
      }
    }

    f32x4 accX[4], accH[4];
    if (layer == 0) {
      const int t1 = j + 1;
      const int xbuf = (t1 >> 3) & 1;
      const int tl = t1 & 7;
      const short8 bAh = *(const short8*)&Xhi[xbuf][tl][col][0];
      const short8 bAl = *(const short8*)&Xlo[xbuf][tl][col][0];
      const short8 bBh = *(const short8*)&H1hi[p][col][8 * q];
      __builtin_amdgcn_s_setprio(1);
      #pragma unroll
      for (int G = 0; G < 4; ++G) accX[G] = MFMA(aAh[G], bAh, biasv[G]);
      #pragma unroll
      for (int G = 0; G < 4; ++G) accH[G] = MFMA(aBh[G], bBh, zerov);
      #pragma unroll
      for (int G = 0; G < 4; ++G) accX[G] = MFMA(aAh[G], bAl, accX[G]);
      #pragma unroll
      for (int G = 0; G < 4; ++G) accX[G] = MFMA(aAl[G], bAh, accX[G]);
      #pragma unroll
      for (int G = 0; G < 4; ++G) accH[G] = MFMA(aBl[G], bBh, accH[G]);
      __builtin_amdgcn_s_setprio(0);
    } else {
      const short8 bAh = *(const short8*)&H1hi[p][col][8 * q];
      const short8 bBh = *(const short8*)&H2hi[1 - p][col][8 * q];
      __builtin_amdgcn_s_setprio(1);
      #pragma unroll
      for (int G = 0; G < 4; ++G) accX[G] = MFMA(aAh[G], bAh, biasv[G]);
      #pragma unroll
      for (int G = 0; G < 4; ++G) accH[G] = MFMA(aBh[G], bBh, zerov);
      #pragma unroll
      for (int G = 0; G < 4; ++G) accX[G] = MFMA(aAl[G], bAh, accX[G]);
      #pragma unroll
      for (int G = 0; G < 4; ++G) accH[G] = MFMA(aBl[G], bBh, accH[G]);
      __builtin_amdgcn_s_setprio(0);
    }

    ushort* dhi = layer ? &H2hi[p][col][ubase] : &H1hi[1 - p][col][ubase];
    ew4_(accX, accH, cst, dhi);
    __syncthreads();
  }

  // ---- epilogue: PB(511) on L1 waves; h1(511)=H1[1], h2(510)=H2[0] ----
  if (layer == 1) {
    f32x4 accX[4], accH[4];
    const short8 bAh = *(const short8*)&H1hi[1][col][8 * q];
    const short8 bBh = *(const short8*)&H2hi[0][col][8 * q];
    #pragma unroll
    for (int G = 0; G < 4; ++G) {
      accX[G] = MFMA(aAh[G], bAh, biasv[G]);
      accX[G] = MFMA(aAl[G], bAh, accX[G]);
      accH[G] = MFMA(aBh[G], bBh, zerov);
      accH[G] = MFMA(aBl[G], bBh, accH[G]);
    }
    ew4_(accX, accH, cst, &H2hi[1][col][ubase]);  // h2(511)
  }
  __syncthreads();

  // ---- head on wave 0: out[b] = tanh(W2 @ relu(W1 @ h2 + b1) + b2) ----
  if (wv == 0) {
    const int f = lane & 15;   // F1 = 16
    const int bg = lane >> 4;  // 4 batches per lane-group
    float w1r[32];
    {
      const float4* wp = (const float4*)(W1 + f * HH);
      #pragma unroll
      for (int qq = 0; qq < 8; ++qq) {
        const float4 v = wp[qq];
        w1r[4*qq]=v.x; w1r[4*qq+1]=v.y; w1r[4*qq+2]=v.z; w1r[4*qq+3]=v.w;
      }
    }
    const float w2 = W2[f], bb1 = b1[f], bb2 = b2[0];
    #pragma unroll
    for (int s = 0; s < 4; ++s) {
      const int b = bg * 4 + s;
      float a = bb1;
      #pragma unroll
      for (int u = 0; u < HH; ++u) {
        const float h = bf16f_(H2hi[1][b][u]);
        a = fmaf(w1r[u], h, a);
      }
      float r = fmaxf(a, 0.f) * w2;
      r += __shfl_xor(r, 1);
      r += __shfl_xor(r, 2);
      r += __shfl_xor(r, 4);
      r += __shfl_xor(r, 8);
      if (f == 0) out[b0 + b] = tanhf_(r + bb2);
    }
  }
}

extern "C" void kernel_launch(void* const* d_in, const int* in_sizes, int n_in,
                              void* d_out, int out_size, void* d_ws, size_t ws_size,
                              hipStream_t stream) {
  const float* X     = (const float*)d_in[0];
  const float* ln_g  = (const float*)d_in[1];
  const float* ln_b  = (const float*)d_in[2];
  const float* Wih0g = (const float*)d_in[3];
  const float* Whh0g = (const float*)d_in[4];
  const float* bih0  = (const float*)d_in[5];
  const float* bhh0  = (const float*)d_in[6];
  const float* Wih1g = (const float*)d_in[7];
  const float* Whh1g = (const float*)d_in[8];
  const float* bih1  = (const float*)d_in[9];
  const float* bhh1  = (const float*)d_in[10];
  const float* W1    = (const float*)d_in[11];
  const float* b1    = (const float*)d_in[12];
  const float* W2    = (const float*)d_in[13];
  const float* b2    = (const float*)d_in[14];
  float* out = (float*)d_out;

  const int Bn = in_sizes[0] / (TT * 8);   // 8192
  dim3 grid(Bn / 16), block(256);
  hipLaunchKernelGGL(lstm_mfma, grid, block, 0, stream,
                     X, ln_g, ln_b, Wih0g, Whh0g, bih0, bhh0,
                     Wih1g, Whh1g, bih1, bhh1, W1, b1, W2, b2, out);
}

// Round 10
// 643.961 us; speedup vs baseline: 1.2962x; 1.0065x over previous
//
#include <hip/hip_runtime.h>
#include <hip/hip_bf16.h>

#define TT 512
#define HH 32

typedef __attribute__((ext_vector_type(8))) short short8;
typedef __attribute__((ext_vector_type(4))) float f32x4;
typedef __attribute__((ext_vector_type(2))) float f32x2;

__device__ __forceinline__ float rcpf_(float x) { return __builtin_amdgcn_rcpf(x); }
// 2^x via a single v_exp_f32 (trans pipe).
__device__ __forceinline__ float expv_(float x) {
  float r;
  asm("v_exp_f32 %0, %1" : "=v"(r) : "v"(x));
  return r;
}
__device__ __forceinline__ f32x2 vfma_(f32x2 a, f32x2 b, f32x2 c) {
  return __builtin_elementwise_fma(a, b, c);
}
__device__ __forceinline__ float tanhf_(float z) {  // head only (1 use/block)
  float a = fabsf(z);
  float e = __expf(-2.f * a);
  return copysignf((1.f - e) * rcpf_(1.f + e), z);
}
__device__ __forceinline__ float bf16f_(ushort u) {
  uint b = (uint)u << 16;
  return __uint_as_float(b);
}

// cheap round-to-nearest bf16: add half-ulp then truncate. Exact-residual split.
// (still used for WEIGHTS, which keep full hi/lo precision)
__device__ __forceinline__ void split8_(const float* w, short8* hi, short8* lo) {
  union { short8 v; ushort u[8]; } H, L;
  #pragma unroll
  for (int i = 0; i < 8; ++i) {
    const uint hb = __float_as_uint(w[i]) + 0x8000u;
    H.u[i] = (ushort)(hb >> 16);
    const float hif = __uint_as_float(hb & 0xffff0000u);
    const uint lb = __float_as_uint(w[i] - hif) + 0x8000u;
    L.u[i] = (ushort)(lb >> 16);
  }
  *hi = H.v; *lo = L.v;
}

// LN one timestep (8 inputs in-lane) -> bf16 (RNE via add-half-ulp) -> X LDS.
// X is now bf16-ONLY (r10): LN output is unit-variance, bf16 err 2^-9 ->
// preact err ~3.3e-4 rms, gate-slope damped; budget ~+1-2e-4 at output.
__device__ __forceinline__ void stageX_(float4 va, float4 vb, int tloc, int col,
                                        ushort (*Xhi)[16][8], const float* lnc) {
  float v[8] = {va.x, va.y, va.z, va.w, vb.x, vb.y, vb.z, vb.w};
  float s = 0.f;
  #pragma unroll
  for (int i = 0; i < 8; ++i) s += v[i];
  const float mu = s * 0.125f;
  float d[8], q2 = 0.f;
  #pragma unroll
  for (int i = 0; i < 8; ++i) { d[i] = v[i] - mu; q2 += d[i] * d[i]; }
  const float inv = __builtin_amdgcn_rsqf(fmaf(q2, 0.125f, 1e-5f));
  union { short8 v8; ushort u[8]; } H;
  #pragma unroll
  for (int i = 0; i < 8; ++i) {
    const float xn = fmaf(d[i] * inv, lnc[i], lnc[8 + i]);
    H.u[i] = (ushort)((__float_as_uint(xn) + 0x8000u) >> 16);
  }
  *(short8*)&Xhi[tloc][col][0] = H.v8;
}

// Elementwise for 4 units as 2x f32x2 (native vector ops -- r5-proven form).
// WEIGHTS/BIASES ARE PRE-SCALED by -log2e (gates i,f,o) / -2*log2e (gate g),
// so MFMA accumulators arrive exp2-ready (r9-proven exact).
// One rcp per unit-pair of gate denominators (prefix products) and one rcp
// across the 4 units' tanh(c) denominators.
// Gate exp args UNCLAMPED: |preact|<=11.7 => arg<=33.8, denominator product
// pp <= 2.7e25 << f32 max. c-args keep min(.,30).
// h stored bf16-only (RNE via add-half-ulp; proven r5).
__device__ __forceinline__ void ew4_(const f32x4* aX, const f32x4* aH, float* cst,
                                     ushort* dhi) {
  const f32x2 mC2 = {-2.88539008f, -2.88539008f};   // -2*log2(e), tail only
  const f32x2 one2 = {1.f, 1.f};
  const f32x2 two2 = {2.f, 2.f};
  const f32x2 m12  = {-1.f, -1.f};
  f32x2 o_[2], cc[2];
  #pragma unroll
  for (int j = 0; j < 2; ++j) {
    // pre-scaled preacts (already *-log2e / *-2log2e)
    const f32x2 pi = (f32x2){aX[0][2*j], aX[0][2*j+1]} + (f32x2){aH[0][2*j], aH[0][2*j+1]};
    const f32x2 pf = (f32x2){aX[1][2*j], aX[1][2*j+1]} + (f32x2){aH[1][2*j], aH[1][2*j+1]};
    const f32x2 pg = (f32x2){aX[2][2*j], aX[2][2*j+1]} + (f32x2){aH[2][2*j], aH[2][2*j+1]};
    const f32x2 po = (f32x2){aX[3][2*j], aX[3][2*j+1]} + (f32x2){aH[3][2*j], aH[3][2*j+1]};
    const f32x2 ei = {expv_(pi.x), expv_(pi.y)};
    const f32x2 ef = {expv_(pf.x), expv_(pf.y)};
    const f32x2 eg = {expv_(pg.x), expv_(pg.y)};
    const f32x2 eo = {expv_(po.x), expv_(po.y)};
    const f32x2 di = ei + one2, df = ef + one2;
    const f32x2 dg = eg + one2, dq = eo + one2;
    const f32x2 p1 = di * df, p2 = dg * dq;
    const f32x2 pp = p1 * p2;
    const f32x2 rr = {rcpf_(pp.x), rcpf_(pp.y)};
    const f32x2 r1 = rr * p2, r2 = rr * p1;           // 1/p1, 1/p2
    const f32x2 iv = r1 * df, fv = r1 * di;           // sig(i), sig(f)
    const f32x2 gv = vfma_(two2, r2 * dq, m12);       // tanh(g)
    o_[j] = r2 * dg;                                  // sig(o)
    const f32x2 cp = {cst[2*j], cst[2*j+1]};
    const f32x2 c = vfma_(fv, cp, iv * gv);
    cst[2*j] = c.x; cst[2*j+1] = c.y;
    cc[j] = c;
  }
  // tanh(c) for 4 units: clamp args, one shared reciprocal
  const f32x2 ca0 = cc[0] * mC2, ca1 = cc[1] * mC2;
  const f32x2 ee0 = {expv_(fminf(ca0.x, 30.f)), expv_(fminf(ca0.y, 30.f))};
  const f32x2 ee1 = {expv_(fminf(ca1.x, 30.f)), expv_(fminf(ca1.y, 30.f))};
  const f32x2 dd0 = ee0 + one2, dd1 = ee1 + one2;
  const float q1 = dd0.x * dd0.y, q2 = dd1.x * dd1.y;
  const float rq = rcpf_(q1 * q2);
  const float s1 = rq * q2, s2 = rq * q1;      // 1/(d0*d1), 1/(d2*d3)
  const f32x2 th0 = {fmaf(2.f, s1 * dd0.y, -1.f), fmaf(2.f, s1 * dd0.x, -1.f)};
  const f32x2 th1 = {fmaf(2.f, s2 * dd1.y, -1.f), fmaf(2.f, s2 * dd1.x, -1.f)};
  const f32x2 h0 = o_[0] * th0, h1 = o_[1] * th1;
  // bf16 pack (round-to-nearest via add-half-ulp), hi only -- proven path
  const float hv[4] = {h0.x, h0.y, h1.x, h1.y};
  uint hp[2];
  #pragma unroll
  for (int pr = 0; pr < 2; ++pr) {
    const uint b0 = (__float_as_uint(hv[pr*2+0]) + 0x8000u) >> 16;
    const uint b1 = (__float_as_uint(hv[pr*2+1]) + 0x8000u) >> 16;
    hp[pr] = b0 | (b1 << 16);
  }
  *(uint2*)dhi = make_uint2(hp[0], hp[1]);
}

#define MFMA(A, B, C) __builtin_amdgcn_mfma_f32_16x16x32_bf16((A), (B), (C), 0, 0, 0)

// 256 threads = 4 waves; 16 batches/block. waves 0,1 = layer0, waves 2,3 = layer1.
// Wave w01 (=wv&1) owns m-tiles {2G+w01}: gate G rows 32G+16*w01+4q+r -> all 4
// gates of units 16*w01+4q+r live in one wave (in-register elementwise).
// Pipeline: iter j computes PA(j+1) (L0 waves) and PB(j) (L1 waves); 1 barrier/t.
// X and h are both bf16-only in LDS (r10/r5); WEIGHTS keep hi/lo residual.
// Both layers now run the same 4-MFMA cluster: accX = bias + (Ahi+Alo)*srcA_hi;
// accH = (Bhi+Blo)*srcB_hi; combined by vector adds in ew4_.
// Weights/biases pre-scaled by -log2e (i,f,o) / -2log2e (g) -> exp2-ready.
// X double-buffered by chunk parity; staging split across both L0 waves.
// #pragma unroll 8 const-folds the (j&7)==6 staging branch + index arith.
// s_setprio(1) around the MFMA cluster (2 independent blocks/CU drift in phase).
__global__ __launch_bounds__(256, 1) void lstm_mfma(
    const float* __restrict__ X,
    const float* __restrict__ ln_g, const float* __restrict__ ln_b,
    const float* __restrict__ Wih0g, const float* __restrict__ Whh0g,
    const float* __restrict__ bih0, const float* __restrict__ bhh0,
    const float* __restrict__ Wih1g, const float* __restrict__ Whh1g,
    const float* __restrict__ bih1, const float* __restrict__ bhh1,
    const float* __restrict__ W1, const float* __restrict__ b1,
    const float* __restrict__ W2, const float* __restrict__ b2,
    float* __restrict__ out)
{
  __shared__ __align__(16) ushort H1hi[2][16][40];
  __shared__ __align__(16) ushort H2hi[2][16][40];
  __shared__ __align__(16) ushort Xhi[2][8][16][8];

  const int tid = threadIdx.x;
  const int wv = tid >> 6;
  const int lane = tid & 63;
  const int q = lane >> 4;       // k-group / D row-group
  const int col = lane & 15;     // batch col (B/D) and A row (m)
  const int layer = wv >> 1;
  const int w01 = wv & 1;
  const int ubase = w01 * 16 + 4 * q;   // first owned unit
  const int b0 = blockIdx.x * 16;

  // ---- A-fragments (weights), once; pre-scaled per gate ----
  short8 aAh[4], aAl[4], aBh[4], aBl[4];
  #pragma unroll
  for (int G = 0; G < 4; ++G) {
    // gate scale: i,f,o -> -log2e ; g (G==2) -> -2*log2e
    const float sc = (G == 2) ? -2.88539008f : -1.44269504f;
    const int row = G * 32 + w01 * 16 + col;
    float w8[8];
    if (layer == 0) {
      if (q == 0) {
        const float4 a = ((const float4*)(Wih0g + row * 8))[0];
        const float4 b = ((const float4*)(Wih0g + row * 8))[1];
        w8[0]=a.x; w8[1]=a.y; w8[2]=a.z; w8[3]=a.w;
        w8[4]=b.x; w8[5]=b.y; w8[6]=b.z; w8[7]=b.w;
      } else {
        #pragma unroll
        for (int i = 0; i < 8; ++i) w8[i] = 0.f;
      }
    } else {
      const float4* P = (const float4*)(Wih1g + row * HH + 8 * q);
      const float4 a = P[0], b = P[1];
      w8[0]=a.x; w8[1]=a.y; w8[2]=a.z; w8[3]=a.w;
      w8[4]=b.x; w8[5]=b.y; w8[6]=b.z; w8[7]=b.w;
    }
    #pragma unroll
    for (int i = 0; i < 8; ++i) w8[i] *= sc;
    split8_(w8, &aAh[G], &aAl[G]);
    {
      const float4* P = (const float4*)((layer ? Whh1g : Whh0g) + row * HH + 8 * q);
      const float4 a = P[0], b = P[1];
      w8[0]=a.x; w8[1]=a.y; w8[2]=a.z; w8[3]=a.w;
      w8[4]=b.x; w8[5]=b.y; w8[6]=b.z; w8[7]=b.w;
    }
    #pragma unroll
    for (int i = 0; i < 8; ++i) w8[i] *= sc;
    split8_(w8, &aBh[G], &aBl[G]);
  }

  // ---- biases as f32x4 vectors (MFMA C operands), pre-scaled ----
  f32x4 biasv[4];
  const f32x4 zerov = {0.f, 0.f, 0.f, 0.f};
  {
    const float* bi = layer ? bih1 : bih0;
    const float* bh = layer ? bhh1 : bhh0;
    #pragma unroll
    for (int G = 0; G < 4; ++G) {
      const float sc = (G == 2) ? -2.88539008f : -1.44269504f;
      #pragma unroll
      for (int r = 0; r < 4; ++r) {
        const int rr = G * 32 + w01 * 16 + 4 * q + r;
        biasv[G][r] = (bi[rr] + bh[rr]) * sc;
      }
    }
  }

  float cst[4] = {0.f, 0.f, 0.f, 0.f};

  float lnc[16];
  float4 xpre0, xpre1;
  const float* xgb = X + (size_t)(b0 + col) * (TT * 8);
  const int tl0 = w01 * 4 + q;   // this lane's staging t-slot

  // ---- prologue: L0 waves stage chunk 0 -> buf 0, prefetch chunk 1 ----
  if (layer == 0) {
    #pragma unroll
    for (int i = 0; i < 8; ++i) { lnc[i] = ln_g[i]; lnc[8 + i] = ln_b[i]; }
    const float4* P = (const float4*)(xgb + tl0 * 8);
    stageX_(P[0], P[1], tl0, col, Xhi[0], lnc);
    const float4* Q = (const float4*)(xgb + (8 + tl0) * 8);
    xpre0 = Q[0]; xpre1 = Q[1];
  }
  if (layer == 1) {
    // zero h2(-1) = H2[1] slice
    *(uint2*)&H2hi[1][col][ubase] = make_uint2(0, 0);
  }
  __syncthreads();

  // ---- t=0 for L0 waves: PA(0) = b0 + Wih0*x(0) (scaled) ----
  if (layer == 0) {
    f32x4 accX[4], accH[4];
    const short8 bAh = *(const short8*)&Xhi[0][0][col][0];
    #pragma unroll
    for (int G = 0; G < 4; ++G) {
      accX[G] = MFMA(aAh[G], bAh, biasv[G]);
      accX[G] = MFMA(aAl[G], bAh, accX[G]);
      accH[G] = zerov;
    }
    ew4_(accX, accH, cst, &H1hi[0][col][ubase]);  // h1(0)
  }
  __syncthreads();

  // ---- main loop: iter j computes PA(j+1) [L0] and PB(j) [L1] ----
  #pragma unroll 8
  for (int j = 0; j < TT - 1; ++j) {
    const int p = j & 1;  // H1[p]=h1(j), H2[1-p]=h2(j-1); write H1[1-p], H2[p]

    if (layer == 0 && (j & 7) == 6) {
      // stage chunk cn=(j+2)/8 into buf cn&1 (first consumed NEXT iter,
      // after this iter's barrier); prefetch chunk cn+1. Split across both
      // L0 waves: each lane stages one t-slot (tl0).
      const int cn = (j + 2) >> 3;
      stageX_(xpre0, xpre1, tl0, col, Xhi[cn & 1], lnc);
      if (cn + 1 < TT / 8) {
        const float4* P = (const float4*)(xgb + ((cn + 1) * 8 + tl0) * 8);
        xpre0 = P[0]; xpre1 = P[1];
      }
    }

    short8 bAh, bBh;
    if (layer == 0) {
      const int t1 = j + 1;
      const int xbuf = (t1 >> 3) & 1;
      const int tl = t1 & 7;
      bAh = *(const short8*)&Xhi[xbuf][tl][col][0];
      bBh = *(const short8*)&H1hi[p][col][8 * q];
    } else {
      bAh = *(const short8*)&H1hi[p][col][8 * q];
      bBh = *(const short8*)&H2hi[1 - p][col][8 * q];
    }

    f32x4 accX[4], accH[4];
    __builtin_amdgcn_s_setprio(1);
    #pragma unroll
    for (int G = 0; G < 4; ++G) accX[G] = MFMA(aAh[G], bAh, biasv[G]);
    #pragma unroll
    for (int G = 0; G < 4; ++G) accH[G] = MFMA(aBh[G], bBh, zerov);
    #pragma unroll
    for (int G = 0; G < 4; ++G) accX[G] = MFMA(aAl[G], bAh, accX[G]);
    #pragma unroll
    for (int G = 0; G < 4; ++G) accH[G] = MFMA(aBl[G], bBh, accH[G]);
    __builtin_amdgcn_s_setprio(0);

    ushort* dhi = layer ? &H2hi[p][col][ubase] : &H1hi[1 - p][col][ubase];
    ew4_(accX, accH, cst, dhi);
    __syncthreads();
  }

  // ---- epilogue: PB(511) on L1 waves; h1(511)=H1[1], h2(510)=H2[0] ----
  if (layer == 1) {
    f32x4 accX[4], accH[4];
    const short8 bAh = *(const short8*)&H1hi[1][col][8 * q];
    const short8 bBh = *(const short8*)&H2hi[0][col][8 * q];
    #pragma unroll
    for (int G = 0; G < 4; ++G) {
      accX[G] = MFMA(aAh[G], bAh, biasv[G]);
      accX[G] = MFMA(aAl[G], bAh, accX[G]);
      accH[G] = MFMA(aBh[G], bBh, zerov);
      accH[G] = MFMA(aBl[G], bBh, accH[G]);
    }
    ew4_(accX, accH, cst, &H2hi[1][col][ubase]);  // h2(511)
  }
  __syncthreads();

  // ---- head on wave 0: out[b] = tanh(W2 @ relu(W1 @ h2 + b1) + b2) ----
  if (wv == 0) {
    const int f = lane & 15;   // F1 = 16
    const int bg = lane >> 4;  // 4 batches per lane-group
    float w1r[32];
    {
      const float4* wp = (const float4*)(W1 + f * HH);
      #pragma unroll
      for (int qq = 0; qq < 8; ++qq) {
        const float4 v = wp[qq];
        w1r[4*qq]=v.x; w1r[4*qq+1]=v.y; w1r[4*qq+2]=v.z; w1r[4*qq+3]=v.w;
      }
    }
    const float w2 = W2[f], bb1 = b1[f], bb2 = b2[0];
    #pragma unroll
    for (int s = 0; s < 4; ++s) {
      const int b = bg * 4 + s;
      float a = bb1;
      #pragma unroll
      for (int u = 0; u < HH; ++u) {
        const float h = bf16f_(H2hi[1][b][u]);
        a = fmaf(w1r[u], h, a);
      }
      float r = fmaxf(a, 0.f) * w2;
      r += __shfl_xor(r, 1);
      r += __shfl_xor(r, 2);
      r += __shfl_xor(r, 4);
      r += __shfl_xor(r, 8);
      if (f == 0) out[b0 + b] = tanhf_(r + bb2);
    }
  }
}

extern "C" void kernel_launch(void* const* d_in, const int* in_sizes, int n_in,
                              void* d_out, int out_size, void* d_ws, size_t ws_size,
                              hipStream_t stream) {
  const float* X     = (const float*)d_in[0];
  const float* ln_g  = (const float*)d_in[1];
  const float* ln_b  = (const float*)d_in[2];
  const float* Wih0g = (const float*)d_in[3];
  const float* Whh0g = (const float*)d_in[4];
  const float* bih0  = (const float*)d_in[5];
  const float* bhh0  = (const float*)d_in[6];
  const float* Wih1g = (const float*)d_in[7];
  const float* Whh1g = (const float*)d_in[8];
  const float* bih1  = (const float*)d_in[9];
  const float* bhh1  = (const float*)d_in[10];
  const float* W1    = (const float*)d_in[11];
  const float* b1    = (const float*)d_in[12];
  const float* W2    = (const float*)d_in[13];
  const float* b2    = (const float*)d_in[14];
  float* out = (float*)d_out;

  const int Bn = in_sizes[0] / (TT * 8);   // 8192
  dim3 grid(Bn / 16), block(256);
  hipLaunchKernelGGL(lstm_mfma, grid, block, 0, stream,
                     X, ln_g, ln_b, Wih0g, Whh0g, bih0, bhh0,
                     Wih1g, Whh1g, bih1, bhh1, W1, b1, W2, b2, out);
}

// Round 11
// 589.080 us; speedup vs baseline: 1.4170x; 1.0932x over previous
//
#include <hip/hip_runtime.h>
#include <hip/hip_bf16.h>

#define TT 512
#define HH 32

typedef __attribute__((ext_vector_type(8))) short short8;
typedef __attribute__((ext_vector_type(4))) float f32x4;
typedef __attribute__((ext_vector_type(2))) float f32x2;

__device__ __forceinline__ float rcpf_(float x) { return __builtin_amdgcn_rcpf(x); }
// 2^x via a single v_exp_f32 (trans pipe).
__device__ __forceinline__ float expv_(float x) {
  float r;
  asm("v_exp_f32 %0, %1" : "=v"(r) : "v"(x));
  return r;
}
__device__ __forceinline__ f32x2 vfma_(f32x2 a, f32x2 b, f32x2 c) {
  return __builtin_elementwise_fma(a, b, c);
}
__device__ __forceinline__ float tanhf_(float z) {  // head only (1 use/block)
  float a = fabsf(z);
  float e = __expf(-2.f * a);
  return copysignf((1.f - e) * rcpf_(1.f + e), z);
}
__device__ __forceinline__ float bf16f_(ushort u) {
  uint b = (uint)u << 16;
  return __uint_as_float(b);
}

// bf16 pack (RNE via add-half-ulp), 8 lanes. r11: weights are bf16-ONLY --
// the lo-residual fragments are dropped (halves the MFMA count; error
// budget justified by the measurement floor observed r5/r9/r10).
__device__ __forceinline__ short8 pack8_(const float* w) {
  union { short8 v; ushort u[8]; } H;
  #pragma unroll
  for (int i = 0; i < 8; ++i)
    H.u[i] = (ushort)((__float_as_uint(w[i]) + 0x8000u) >> 16);
  return H.v;
}

// LN one timestep (8 inputs in-lane) -> bf16 (RNE) -> X LDS (bf16-only, r10).
__device__ __forceinline__ void stageX_(float4 va, float4 vb, int tloc, int col,
                                        ushort (*Xhi)[16][8], const float* lnc) {
  float v[8] = {va.x, va.y, va.z, va.w, vb.x, vb.y, vb.z, vb.w};
  float s = 0.f;
  #pragma unroll
  for (int i = 0; i < 8; ++i) s += v[i];
  const float mu = s * 0.125f;
  float d[8], q2 = 0.f;
  #pragma unroll
  for (int i = 0; i < 8; ++i) { d[i] = v[i] - mu; q2 += d[i] * d[i]; }
  const float inv = __builtin_amdgcn_rsqf(fmaf(q2, 0.125f, 1e-5f));
  float xn[8];
  #pragma unroll
  for (int i = 0; i < 8; ++i) xn[i] = fmaf(d[i] * inv, lnc[i], lnc[8 + i]);
  *(short8*)&Xhi[tloc][col][0] = pack8_(xn);
}

// Elementwise for 4 units as 2x f32x2 (native vector ops -- r5-proven form).
// WEIGHTS/BIASES ARE PRE-SCALED by -log2e (gates i,f,o) / -2*log2e (gate g),
// so MFMA accumulators arrive exp2-ready (r9-proven exact).
// One rcp per unit-pair of gate denominators (prefix products) and one rcp
// across the 4 units' tanh(c) denominators.
// Gate exp args UNCLAMPED: |preact|<=11.7 => arg<=33.8, denominator product
// pp <= 2.7e25 << f32 max. c-args keep min(.,30).
// h stored bf16-only (RNE; proven r5).
__device__ __forceinline__ void ew4_(const f32x4* aX, const f32x4* aH, float* cst,
                                     ushort* dhi) {
  const f32x2 mC2 = {-2.88539008f, -2.88539008f};   // -2*log2(e), tail only
  const f32x2 one2 = {1.f, 1.f};
  const f32x2 two2 = {2.f, 2.f};
  const f32x2 m12  = {-1.f, -1.f};
  f32x2 o_[2], cc[2];
  #pragma unroll
  for (int j = 0; j < 2; ++j) {
    // pre-scaled preacts (already *-log2e / *-2log2e)
    const f32x2 pi = (f32x2){aX[0][2*j], aX[0][2*j+1]} + (f32x2){aH[0][2*j], aH[0][2*j+1]};
    const f32x2 pf = (f32x2){aX[1][2*j], aX[1][2*j+1]} + (f32x2){aH[1][2*j], aH[1][2*j+1]};
    const f32x2 pg = (f32x2){aX[2][2*j], aX[2][2*j+1]} + (f32x2){aH[2][2*j], aH[2][2*j+1]};
    const f32x2 po = (f32x2){aX[3][2*j], aX[3][2*j+1]} + (f32x2){aH[3][2*j], aH[3][2*j+1]};
    const f32x2 ei = {expv_(pi.x), expv_(pi.y)};
    const f32x2 ef = {expv_(pf.x), expv_(pf.y)};
    const f32x2 eg = {expv_(pg.x), expv_(pg.y)};
    const f32x2 eo = {expv_(po.x), expv_(po.y)};
    const f32x2 di = ei + one2, df = ef + one2;
    const f32x2 dg = eg + one2, dq = eo + one2;
    const f32x2 p1 = di * df, p2 = dg * dq;
    const f32x2 pp = p1 * p2;
    const f32x2 rr = {rcpf_(pp.x), rcpf_(pp.y)};
    const f32x2 r1 = rr * p2, r2 = rr * p1;           // 1/p1, 1/p2
    const f32x2 iv = r1 * df, fv = r1 * di;           // sig(i), sig(f)
    const f32x2 gv = vfma_(two2, r2 * dq, m12);       // tanh(g)
    o_[j] = r2 * dg;                                  // sig(o)
    const f32x2 cp = {cst[2*j], cst[2*j+1]};
    const f32x2 c = vfma_(fv, cp, iv * gv);
    cst[2*j] = c.x; cst[2*j+1] = c.y;
    cc[j] = c;
  }
  // tanh(c) for 4 units: clamp args, one shared reciprocal
  const f32x2 ca0 = cc[0] * mC2, ca1 = cc[1] * mC2;
  const f32x2 ee0 = {expv_(fminf(ca0.x, 30.f)), expv_(fminf(ca0.y, 30.f))};
  const f32x2 ee1 = {expv_(fminf(ca1.x, 30.f)), expv_(fminf(ca1.y, 30.f))};
  const f32x2 dd0 = ee0 + one2, dd1 = ee1 + one2;
  const float q1 = dd0.x * dd0.y, q2 = dd1.x * dd1.y;
  const float rq = rcpf_(q1 * q2);
  const float s1 = rq * q2, s2 = rq * q1;      // 1/(d0*d1), 1/(d2*d3)
  const f32x2 th0 = {fmaf(2.f, s1 * dd0.y, -1.f), fmaf(2.f, s1 * dd0.x, -1.f)};
  const f32x2 th1 = {fmaf(2.f, s2 * dd1.y, -1.f), fmaf(2.f, s2 * dd1.x, -1.f)};
  const f32x2 h0 = o_[0] * th0, h1 = o_[1] * th1;
  // bf16 pack (RNE), hi only -- proven path
  const float hv[4] = {h0.x, h0.y, h1.x, h1.y};
  uint hp[2];
  #pragma unroll
  for (int pr = 0; pr < 2; ++pr) {
    const uint b0 = (__float_as_uint(hv[pr*2+0]) + 0x8000u) >> 16;
    const uint b1 = (__float_as_uint(hv[pr*2+1]) + 0x8000u) >> 16;
    hp[pr] = b0 | (b1 << 16);
  }
  *(uint2*)dhi = make_uint2(hp[0], hp[1]);
}

#define MFMA(A, B, C) __builtin_amdgcn_mfma_f32_16x16x32_bf16((A), (B), (C), 0, 0, 0)

// 256 threads = 4 waves; 16 batches/block. waves 0,1 = layer0, waves 2,3 = layer1.
// Wave w01 (=wv&1) owns m-tiles {2G+w01}: gate G rows 32G+16*w01+4q+r -> all 4
// gates of units 16*w01+4q+r live in one wave (in-register elementwise).
// Pipeline: iter j computes PA(j+1) (L0 waves) and PB(j) (L1 waves); 1 barrier/t.
// r11: X, h, AND WEIGHTS all bf16-only -- 8 MFMAs/wave-iter (1-deep chains):
//   accX[G] = bias + Wx_hi * src_hi ; accH[G] = Wh_hi * src_hi.
// Weights/biases pre-scaled by -log2e (i,f,o) / -2log2e (g) -> exp2-ready.
// X double-buffered by chunk parity; staging split across both L0 waves.
// #pragma unroll 8 const-folds the (j&7)==6 staging branch + index arith.
// s_setprio(1) around the MFMA cluster (2 independent blocks/CU drift in phase).
__global__ __launch_bounds__(256, 1) void lstm_mfma(
    const float* __restrict__ X,
    const float* __restrict__ ln_g, const float* __restrict__ ln_b,
    const float* __restrict__ Wih0g, const float* __restrict__ Whh0g,
    const float* __restrict__ bih0, const float* __restrict__ bhh0,
    const float* __restrict__ Wih1g, const float* __restrict__ Whh1g,
    const float* __restrict__ bih1, const float* __restrict__ bhh1,
    const float* __restrict__ W1, const float* __restrict__ b1,
    const float* __restrict__ W2, const float* __restrict__ b2,
    float* __restrict__ out)
{
  __shared__ __align__(16) ushort H1hi[2][16][40];
  __shared__ __align__(16) ushort H2hi[2][16][40];
  __shared__ __align__(16) ushort Xhi[2][8][16][8];

  const int tid = threadIdx.x;
  const int wv = tid >> 6;
  const int lane = tid & 63;
  const int q = lane >> 4;       // k-group / D row-group
  const int col = lane & 15;     // batch col (B/D) and A row (m)
  const int layer = wv >> 1;
  const int w01 = wv & 1;
  const int ubase = w01 * 16 + 4 * q;   // first owned unit
  const int b0 = blockIdx.x * 16;

  // ---- A-fragments (weights), once; pre-scaled per gate; bf16-only ----
  short8 aAh[4], aBh[4];
  #pragma unroll
  for (int G = 0; G < 4; ++G) {
    // gate scale: i,f,o -> -log2e ; g (G==2) -> -2*log2e
    const float sc = (G == 2) ? -2.88539008f : -1.44269504f;
    const int row = G * 32 + w01 * 16 + col;
    float w8[8];
    if (layer == 0) {
      if (q == 0) {
        const float4 a = ((const float4*)(Wih0g + row * 8))[0];
        const float4 b = ((const float4*)(Wih0g + row * 8))[1];
        w8[0]=a.x; w8[1]=a.y; w8[2]=a.z; w8[3]=a.w;
        w8[4]=b.x; w8[5]=b.y; w8[6]=b.z; w8[7]=b.w;
      } else {
        #pragma unroll
        for (int i = 0; i < 8; ++i) w8[i] = 0.f;
      }
    } else {
      const float4* P = (const float4*)(Wih1g + row * HH + 8 * q);
      const float4 a = P[0], b = P[1];
      w8[0]=a.x; w8[1]=a.y; w8[2]=a.z; w8[3]=a.w;
      w8[4]=b.x; w8[5]=b.y; w8[6]=b.z; w8[7]=b.w;
    }
    #pragma unroll
    for (int i = 0; i < 8; ++i) w8[i] *= sc;
    aAh[G] = pack8_(w8);
    {
      const float4* P = (const float4*)((layer ? Whh1g : Whh0g) + row * HH + 8 * q);
      const float4 a = P[0], b = P[1];
      w8[0]=a.x; w8[1]=a.y; w8[2]=a.z; w8[3]=a.w;
      w8[4]=b.x; w8[5]=b.y; w8[6]=b.z; w8[7]=b.w;
    }
    #pragma unroll
    for (int i = 0; i < 8; ++i) w8[i] *= sc;
    aBh[G] = pack8_(w8);
  }

  // ---- biases as f32x4 vectors (MFMA C operands), pre-scaled ----
  f32x4 biasv[4];
  const f32x4 zerov = {0.f, 0.f, 0.f, 0.f};
  {
    const float* bi = layer ? bih1 : bih0;
    const float* bh = layer ? bhh1 : bhh0;
    #pragma unroll
    for (int G = 0; G < 4; ++G) {
      const float sc = (G == 2) ? -2.88539008f : -1.44269504f;
      #pragma unroll
      for (int r = 0; r < 4; ++r) {
        const int rr = G * 32 + w01 * 16 + 4 * q + r;
        biasv[G][r] = (bi[rr] + bh[rr]) * sc;
      }
    }
  }

  float cst[4] = {0.f, 0.f, 0.f, 0.f};

  float lnc[16];
  float4 xpre0, xpre1;
  const float* xgb = X + (size_t)(b0 + col) * (TT * 8);
  const int tl0 = w01 * 4 + q;   // this lane's staging t-slot

  // ---- prologue: L0 waves stage chunk 0 -> buf 0, prefetch chunk 1 ----
  if (layer == 0) {
    #pragma unroll
    for (int i = 0; i < 8; ++i) { lnc[i] = ln_g[i]; lnc[8 + i] = ln_b[i]; }
    const float4* P = (const float4*)(xgb + tl0 * 8);
    stageX_(P[0], P[1], tl0, col, Xhi[0], lnc);
    const float4* Q = (const float4*)(xgb + (8 + tl0) * 8);
    xpre0 = Q[0]; xpre1 = Q[1];
  }
  if (layer == 1) {
    // zero h2(-1) = H2[1] slice
    *(uint2*)&H2hi[1][col][ubase] = make_uint2(0, 0);
  }
  __syncthreads();

  // ---- t=0 for L0 waves: PA(0) = b0 + Wih0*x(0) (scaled) ----
  if (layer == 0) {
    f32x4 accX[4], accH[4];
    const short8 bAh = *(const short8*)&Xhi[0][0][col][0];
    #pragma unroll
    for (int G = 0; G < 4; ++G) {
      accX[G] = MFMA(aAh[G], bAh, biasv[G]);
      accH[G] = zerov;
    }
    ew4_(accX, accH, cst, &H1hi[0][col][ubase]);  // h1(0)
  }
  __syncthreads();

  // ---- main loop: iter j computes PA(j+1) [L0] and PB(j) [L1] ----
  #pragma unroll 8
  for (int j = 0; j < TT - 1; ++j) {
    const int p = j & 1;  // H1[p]=h1(j), H2[1-p]=h2(j-1); write H1[1-p], H2[p]

    if (layer == 0 && (j & 7) == 6) {
      // stage chunk cn=(j+2)/8 into buf cn&1 (first consumed NEXT iter,
      // after this iter's barrier); prefetch chunk cn+1. Split across both
      // L0 waves: each lane stages one t-slot (tl0).
      const int cn = (j + 2) >> 3;
      stageX_(xpre0, xpre1, tl0, col, Xhi[cn & 1], lnc);
      if (cn + 1 < TT / 8) {
        const float4* P = (const float4*)(xgb + ((cn + 1) * 8 + tl0) * 8);
        xpre0 = P[0]; xpre1 = P[1];
      }
    }

    short8 bAh, bBh;
    if (layer == 0) {
      const int t1 = j + 1;
      const int xbuf = (t1 >> 3) & 1;
      const int tl = t1 & 7;
      bAh = *(const short8*)&Xhi[xbuf][tl][col][0];
      bBh = *(const short8*)&H1hi[p][col][8 * q];
    } else {
      bAh = *(const short8*)&H1hi[p][col][8 * q];
      bBh = *(const short8*)&H2hi[1 - p][col][8 * q];
    }

    f32x4 accX[4], accH[4];
    __builtin_amdgcn_s_setprio(1);
    #pragma unroll
    for (int G = 0; G < 4; ++G) accX[G] = MFMA(aAh[G], bAh, biasv[G]);
    #pragma unroll
    for (int G = 0; G < 4; ++G) accH[G] = MFMA(aBh[G], bBh, zerov);
    __builtin_amdgcn_s_setprio(0);

    ushort* dhi = layer ? &H2hi[p][col][ubase] : &H1hi[1 - p][col][ubase];
    ew4_(accX, accH, cst, dhi);
    __syncthreads();
  }

  // ---- epilogue: PB(511) on L1 waves; h1(511)=H1[1], h2(510)=H2[0] ----
  if (layer == 1) {
    f32x4 accX[4], accH[4];
    const short8 bAh = *(const short8*)&H1hi[1][col][8 * q];
    const short8 bBh = *(const short8*)&H2hi[0][col][8 * q];
    #pragma unroll
    for (int G = 0; G < 4; ++G) {
      accX[G] = MFMA(aAh[G], bAh, biasv[G]);
      accH[G] = MFMA(aBh[G], bBh, zerov);
    }
    ew4_(accX, accH, cst, &H2hi[1][col][ubase]);  // h2(511)
  }
  __syncthreads();

  // ---- head on wave 0: out[b] = tanh(W2 @ relu(W1 @ h2 + b1) + b2) ----
  if (wv == 0) {
    const int f = lane & 15;   // F1 = 16
    const int bg = lane >> 4;  // 4 batches per lane-group
    float w1r[32];
    {
      const float4* wp = (const float4*)(W1 + f * HH);
      #pragma unroll
      for (int qq = 0; qq < 8; ++qq) {
        const float4 v = wp[qq];
        w1r[4*qq]=v.x; w1r[4*qq+1]=v.y; w1r[4*qq+2]=v.z; w1r[4*qq+3]=v.w;
      }
    }
    const float w2 = W2[f], bb1 = b1[f], bb2 = b2[0];
    #pragma unroll
    for (int s = 0; s < 4; ++s) {
      const int b = bg * 4 + s;
      float a = bb1;
      #pragma unroll
      for (int u = 0; u < HH; ++u) {
        const float h = bf16f_(H2hi[1][b][u]);
        a = fmaf(w1r[u], h, a);
      }
      float r = fmaxf(a, 0.f) * w2;
      r += __shfl_xor(r, 1);
      r += __shfl_xor(r, 2);
      r += __shfl_xor(r, 4);
      r += __shfl_xor(r, 8);
      if (f == 0) out[b0 + b] = tanhf_(r + bb2);
    }
  }
}

extern "C" void kernel_launch(void* const* d_in, const int* in_sizes, int n_in,
                              void* d_out, int out_size, void* d_ws, size_t ws_size,
                              hipStream_t stream) {
  const float* X     = (const float*)d_in[0];
  const float* ln_g  = (const float*)d_in[1];
  const float* ln_b  = (const float*)d_in[2];
  const float* Wih0g = (const float*)d_in[3];
  const float* Whh0g = (const float*)d_in[4];
  const float* bih0  = (const float*)d_in[5];
  const float* bhh0  = (const float*)d_in[6];
  const float* Wih1g = (const float*)d_in[7];
  const float* Whh1g = (const float*)d_in[8];
  const float* bih1  = (const float*)d_in[9];
  const float* bhh1  = (const float*)d_in[10];
  const float* W1    = (const float*)d_in[11];
  const float* b1    = (const float*)d_in[12];
  const float* W2    = (const float*)d_in[13];
  const float* b2    = (const float*)d_in[14];
  float* out = (float*)d_out;

  const int Bn = in_sizes[0] / (TT * 8);   // 8192
  dim3 grid(Bn / 16), block(256);
  hipLaunchKernelGGL(lstm_mfma, grid, block, 0, stream,
                     X, ln_g, ln_b, Wih0g, Whh0g, bih0, bhh0,
                     Wih1g, Whh1g, bih1, bhh1, W1, b1, W2, b2, out);
}